// Round 1
// baseline (525.556 us; speedup 1.0000x reference)
//
#include <hip/hip_runtime.h>
#include <math.h>

#define NB 32
#define CC 1024
#define SS 784
#define DD 128
#define KK 64
#define OUTD 1024
#define KD 8192          // K*D
#define VSPLIT 8         // split-K for vlad GEMM (784 = 8*98)
#define PSPLIT 16        // split-K for projection (8192 = 16*512)

// workspace layout (floats)
#define WS_XN     0                           // (N,D,S) normalized descriptors
#define WS_SA     (WS_XN + NB*DD*SS)          // (N,K,S) soft assign
#define WS_VLADP  (WS_SA + NB*KK*SS)          // (N,VSPLIT,K*D) vlad partials
#define WS_SASUMP (WS_VLADP + NB*VSPLIT*KD)   // (N,VSPLIT,K) sasum partials
#define WS_VLADN  (WS_SASUMP + NB*VSPLIT*KK)  // (N,K*D) normalized vlad
#define WS_OUTP   (WS_VLADN + NB*KD)          // (PSPLIT,N,OUT) proj partials

// ---------------------------------------------------------------------------
// Kernel A: xf = Wpool @ x_n + bpool, then L2-normalize over D (axis=1).
// Block covers full D=128 rows x 64 s-cols.  grid (ceil(S/64)=13, N)
// ---------------------------------------------------------------------------
__global__ __launch_bounds__(256)
void pool_norm_kernel(const float* __restrict__ x, const float* __restrict__ Wpool,
                      const float* __restrict__ bpool, float* __restrict__ xn)
{
    const int n  = blockIdx.y;
    const int s0 = blockIdx.x * 64;
    const int t  = threadIdx.x;
    const int tx = t & 15;   // s group: s_local = tx + 16*j
    const int ty = t >> 4;   // d group: d = ty*8 + i

    __shared__ float As[16][132];  // [c][d], stride 132 (pad: store 2-way only)
    __shared__ float Xs[16][64];   // [c][s]
    __shared__ float red[16][64];  // [ty][s] partial sums of squares

    float acc[8][4];
#pragma unroll
    for (int i = 0; i < 8; i++)
#pragma unroll
        for (int j = 0; j < 4; j++) acc[i][j] = 0.f;

    const float* xptr = x + (size_t)n * CC * SS;

    for (int kk = 0; kk < CC; kk += 16) {
        // Wpool tile: d=0..127, c=kk..kk+15
        {
            const int c = t & 15, dd = t >> 4;
#pragma unroll
            for (int i = 0; i < 8; i++)
                As[c][dd + 16 * i] = Wpool[(dd + 16 * i) * CC + kk + c];
        }
        // x tile: c rows, 64 s cols (coalesced 256B runs)
        {
            const int sl = t & 63, cl = t >> 6;
#pragma unroll
            for (int i = 0; i < 4; i++) {
                const int c = cl + 4 * i;
                const int s = s0 + sl;
                Xs[c][sl] = (s < SS) ? xptr[(kk + c) * SS + s] : 0.f;
            }
        }
        __syncthreads();
#pragma unroll
        for (int cc = 0; cc < 16; cc++) {
            float a[8], b[4];
#pragma unroll
            for (int i = 0; i < 8; i++) a[i] = As[cc][ty * 8 + i];
#pragma unroll
            for (int j = 0; j < 4; j++) b[j] = Xs[cc][tx + 16 * j];
#pragma unroll
            for (int i = 0; i < 8; i++)
#pragma unroll
                for (int j = 0; j < 4; j++) acc[i][j] += a[i] * b[j];
        }
        __syncthreads();
    }

    // bias
#pragma unroll
    for (int i = 0; i < 8; i++) {
        const float bv = bpool[ty * 8 + i];
#pragma unroll
        for (int j = 0; j < 4; j++) acc[i][j] += bv;
    }

    // per-s sum of squares over the 128 d values
#pragma unroll
    for (int j = 0; j < 4; j++) {
        float p = 0.f;
#pragma unroll
        for (int i = 0; i < 8; i++) p += acc[i][j] * acc[i][j];
        red[ty][tx + 16 * j] = p;
    }
    __syncthreads();

    float* xnp = xn + (size_t)n * DD * SS;
#pragma unroll
    for (int j = 0; j < 4; j++) {
        const int sl = tx + 16 * j;
        float sum = 0.f;
#pragma unroll
        for (int u = 0; u < 16; u++) sum += red[u][sl];
        const float scale = 1.f / fmaxf(sqrtf(sum), 1e-12f);
        const int s = s0 + sl;
        if (s < SS) {
#pragma unroll
            for (int i = 0; i < 8; i++)
                xnp[(ty * 8 + i) * SS + s] = acc[i][j] * scale;
        }
    }
}

// ---------------------------------------------------------------------------
// Kernel C: sa = softmax_k(Wconv @ xn + bconv).  One thread per s.
// grid (ceil(S/256)=4, N), block 256.  Wconv (64x128) cached in LDS.
// ---------------------------------------------------------------------------
__global__ __launch_bounds__(256)
void assign_softmax_kernel(const float* __restrict__ xn, const float* __restrict__ Wconv,
                           const float* __restrict__ bconv, float* __restrict__ sa)
{
    __shared__ float Wc[KK * DD];   // 32 KB
    __shared__ float bcs[KK];
    const int t = threadIdx.x;
#pragma unroll
    for (int i = 0; i < 32; i++) Wc[t + 256 * i] = Wconv[t + 256 * i];
    if (t < KK) bcs[t] = bconv[t];
    __syncthreads();

    const int n = blockIdx.y;
    const int s = blockIdx.x * 256 + t;
    if (s >= SS) return;

    float acc[KK];
#pragma unroll
    for (int k = 0; k < KK; k++) acc[k] = bcs[k];

    const float* xp = xn + (size_t)n * DD * SS + s;
    for (int d0 = 0; d0 < DD; d0 += 8) {
        float xv[8];
#pragma unroll
        for (int dd = 0; dd < 8; dd++) xv[dd] = xp[(d0 + dd) * SS];
#pragma unroll
        for (int k = 0; k < KK; k++) {
            const float4 w0 = *(const float4*)&Wc[k * DD + d0];
            const float4 w1 = *(const float4*)&Wc[k * DD + d0 + 4];
            acc[k] += w0.x * xv[0] + w0.y * xv[1] + w0.z * xv[2] + w0.w * xv[3]
                    + w1.x * xv[4] + w1.y * xv[5] + w1.z * xv[6] + w1.w * xv[7];
        }
    }

    float m = -1e30f;
#pragma unroll
    for (int k = 0; k < KK; k++) m = fmaxf(m, acc[k]);
    float sum = 0.f;
#pragma unroll
    for (int k = 0; k < KK; k++) { acc[k] = expf(acc[k] - m); sum += acc[k]; }
    const float r = 1.f / sum;
    float* sap = sa + ((size_t)n * KK) * SS + s;
#pragma unroll
    for (int k = 0; k < KK; k++) sap[k * SS] = acc[k] * r;
}

// ---------------------------------------------------------------------------
// Kernel D: vlad partial GEMM: vladp[n,sp,k,d] = sum_{s in range} sa[k,s]*xn[d,s]
// plus partial sasum.  grid (VSPLIT, N), block 256, s-range = 98 each.
// ---------------------------------------------------------------------------
__global__ __launch_bounds__(256)
void vlad_partial_kernel(const float* __restrict__ xn, const float* __restrict__ sa,
                         float* __restrict__ vladp, float* __restrict__ sasump)
{
    const int sp = blockIdx.x;
    const int n  = blockIdx.y;
    const int t  = threadIdx.x;
    const int tx = t & 15;   // d = tx + 16*i
    const int ty = t >> 4;   // k = ty + 16*j

    __shared__ float XnS[DD][33];
    __shared__ float SaS[KK][33];

    float acc[4][8];
#pragma unroll
    for (int j = 0; j < 4; j++)
#pragma unroll
        for (int i = 0; i < 8; i++) acc[j][i] = 0.f;
    float local_sasum = 0.f;

    const int s_begin = sp * 98;
    const float* xp = xn + (size_t)n * DD * SS;
    const float* sp_ = sa + (size_t)n * KK * SS;

    for (int ch = 0; ch < 4; ch++) {           // 4 chunks of 32 cover 98 (last partial)
        const int sb = s_begin + ch * 32;
        {
            const int si = t & 31, dl = t >> 5;
#pragma unroll
            for (int i = 0; i < 16; i++) {
                const int d = dl + 8 * i;
                const int s = sb + si;
                XnS[d][si] = (s < s_begin + 98) ? xp[d * SS + s] : 0.f;
            }
#pragma unroll
            for (int i = 0; i < 8; i++) {
                const int k = dl + 8 * i;
                const int s = sb + si;
                SaS[k][si] = (s < s_begin + 98) ? sp_[k * SS + s] : 0.f;
            }
        }
        __syncthreads();
        if (t < KK) {
#pragma unroll
            for (int si = 0; si < 32; si++) local_sasum += SaS[t][si];
        }
#pragma unroll
        for (int si = 0; si < 32; si++) {
            float a[4], b[8];
#pragma unroll
            for (int j = 0; j < 4; j++) a[j] = SaS[ty + 16 * j][si];
#pragma unroll
            for (int i = 0; i < 8; i++) b[i] = XnS[tx + 16 * i][si];
#pragma unroll
            for (int j = 0; j < 4; j++)
#pragma unroll
                for (int i = 0; i < 8; i++) acc[j][i] += a[j] * b[i];
        }
        __syncthreads();
    }

    float* vp = vladp + ((size_t)n * VSPLIT + sp) * KD;
#pragma unroll
    for (int j = 0; j < 4; j++)
#pragma unroll
        for (int i = 0; i < 8; i++)
            vp[(ty + 16 * j) * DD + (tx + 16 * i)] = acc[j][i];
    if (t < KK) sasump[((size_t)n * VSPLIT + sp) * KK + t] = local_sasum;
}

// ---------------------------------------------------------------------------
// Kernel D2: reduce partials, subtract centroids*sasum, L2-norm over k (axis=1),
// write vladn (N, K*D).  grid (N), block 256: thread owns d=t&127, k-half t>>7.
// ---------------------------------------------------------------------------
__global__ __launch_bounds__(256)
void vlad_finish_kernel(const float* __restrict__ vladp, const float* __restrict__ sasump,
                        const float* __restrict__ centroids, float* __restrict__ vladn)
{
    const int n = blockIdx.x;
    const int t = threadIdx.x;
    const int d = t & 127;
    const int kh = t >> 7;   // 0/1: k = kh*32 + j

    __shared__ float sas[KK];
    __shared__ float red2[2][128];

    if (t < KK) {
        float ssum = 0.f;
#pragma unroll
        for (int p = 0; p < VSPLIT; p++) ssum += sasump[((size_t)n * VSPLIT + p) * KK + t];
        sas[t] = ssum;
    }
    __syncthreads();

    float v[32];
    float ssp = 0.f;
#pragma unroll
    for (int j = 0; j < 32; j++) {
        const int k = kh * 32 + j;
        float a = 0.f;
#pragma unroll
        for (int p = 0; p < VSPLIT; p++)
            a += vladp[((size_t)n * VSPLIT + p) * KD + k * DD + d];
        a -= centroids[k * DD + d] * sas[k];
        v[j] = a;
        ssp += a * a;
    }
    red2[kh][d] = ssp;
    __syncthreads();
    const float scale = 1.f / fmaxf(sqrtf(red2[0][d] + red2[1][d]), 1e-12f);

    float* vo = vladn + (size_t)n * KD;
#pragma unroll
    for (int j = 0; j < 32; j++) {
        const int k = kh * 32 + j;
        vo[k * DD + d] = v[j] * scale;
    }
}

// ---------------------------------------------------------------------------
// Kernel F: projection partials: outp[p,n,o] = vladn[n, c-range] . Wproj[o, c-range]
// grid (OUT/64=16, PSPLIT=16), block 256.
// ---------------------------------------------------------------------------
__global__ __launch_bounds__(256)
void proj_partial_kernel(const float* __restrict__ vladn, const float* __restrict__ Wproj,
                         float* __restrict__ outp)
{
    const int o0 = blockIdx.x * 64;
    const int c0 = blockIdx.y * (KD / PSPLIT);   // 512-wide K slice
    const int t  = threadIdx.x;
    const int ow = t & 31;   // o = o0 + ow + 32*i
    const int nw = t >> 5;   // n = nw + 8*j

    __shared__ float Ws[64][33];
    __shared__ float Vs[32][33];

    float acc[2][4];
#pragma unroll
    for (int i = 0; i < 2; i++)
#pragma unroll
        for (int j = 0; j < 4; j++) acc[i][j] = 0.f;

    for (int cc0 = c0; cc0 < c0 + KD / PSPLIT; cc0 += 32) {
        {
            const int col = t & 31, row = t >> 5;
#pragma unroll
            for (int i = 0; i < 8; i++)
                Ws[row + 8 * i][col] = Wproj[(size_t)(o0 + row + 8 * i) * KD + cc0 + col];
#pragma unroll
            for (int i = 0; i < 4; i++)
                Vs[row + 8 * i][col] = vladn[(size_t)(row + 8 * i) * KD + cc0 + col];
        }
        __syncthreads();
#pragma unroll
        for (int cc = 0; cc < 32; cc++) {
            float wv[2], vv[4];
#pragma unroll
            for (int i = 0; i < 2; i++) wv[i] = Ws[ow + 32 * i][cc];
#pragma unroll
            for (int j = 0; j < 4; j++) vv[j] = Vs[nw + 8 * j][cc];
#pragma unroll
            for (int i = 0; i < 2; i++)
#pragma unroll
                for (int j = 0; j < 4; j++) acc[i][j] += wv[i] * vv[j];
        }
        __syncthreads();
    }

#pragma unroll
    for (int i = 0; i < 2; i++)
#pragma unroll
        for (int j = 0; j < 4; j++) {
            const int o = o0 + ow + 32 * i;
            const int n = nw + 8 * j;
            outp[((size_t)blockIdx.y * NB + n) * OUTD + o] = acc[i][j];
        }
}

// ---------------------------------------------------------------------------
// Kernel G: sum projection partials + bproj, final L2 norm over OUT, write d_out.
// grid (N), block 256; thread handles o = t + 256*i.
// ---------------------------------------------------------------------------
__global__ __launch_bounds__(256)
void final_norm_kernel(const float* __restrict__ outp, const float* __restrict__ bproj,
                       float* __restrict__ out)
{
    const int n = blockIdx.x;
    const int t = threadIdx.x;

    float v[4];
    float ssp = 0.f;
#pragma unroll
    for (int i = 0; i < 4; i++) {
        const int o = t + 256 * i;
        float a = 0.f;
#pragma unroll
        for (int p = 0; p < PSPLIT; p++) a += outp[((size_t)p * NB + n) * OUTD + o];
        a += bproj[o];
        v[i] = a;
        ssp += a * a;
    }

    // wave reduce then cross-wave via LDS
#pragma unroll
    for (int off = 32; off > 0; off >>= 1) ssp += __shfl_down(ssp, off, 64);
    __shared__ float rs[4];
    if ((t & 63) == 0) rs[t >> 6] = ssp;
    __syncthreads();
    const float total = rs[0] + rs[1] + rs[2] + rs[3];
    const float scale = 1.f / fmaxf(sqrtf(total), 1e-12f);

#pragma unroll
    for (int i = 0; i < 4; i++) out[(size_t)n * OUTD + t + 256 * i] = v[i] * scale;
}

// ---------------------------------------------------------------------------
extern "C" void kernel_launch(void* const* d_in, const int* in_sizes, int n_in,
                              void* d_out, int out_size, void* d_ws, size_t ws_size,
                              hipStream_t stream)
{
    const float* x         = (const float*)d_in[0];
    const float* Wpool     = (const float*)d_in[1];
    const float* bpool     = (const float*)d_in[2];
    const float* Wconv     = (const float*)d_in[3];
    const float* bconv     = (const float*)d_in[4];
    const float* centroids = (const float*)d_in[5];
    const float* Wproj     = (const float*)d_in[6];
    const float* bproj     = (const float*)d_in[7];
    float* out = (float*)d_out;
    float* ws  = (float*)d_ws;

    float* xn     = ws + WS_XN;
    float* sa     = ws + WS_SA;
    float* vladp  = ws + WS_VLADP;
    float* sasump = ws + WS_SASUMP;
    float* vladn  = ws + WS_VLADN;
    float* outp   = ws + WS_OUTP;

    pool_norm_kernel<<<dim3(13, NB), 256, 0, stream>>>(x, Wpool, bpool, xn);
    assign_softmax_kernel<<<dim3(4, NB), 256, 0, stream>>>(xn, Wconv, bconv, sa);
    vlad_partial_kernel<<<dim3(VSPLIT, NB), 256, 0, stream>>>(xn, sa, vladp, sasump);
    vlad_finish_kernel<<<dim3(NB), 256, 0, stream>>>(vladp, sasump, centroids, vladn);
    proj_partial_kernel<<<dim3(OUTD / 64, PSPLIT), 256, 0, stream>>>(vladn, Wproj, outp);
    final_norm_kernel<<<dim3(NB), 256, 0, stream>>>(outp, bproj, out);
}

// Round 2
// 341.289 us; speedup vs baseline: 1.5399x; 1.5399x over previous
//
#include <hip/hip_runtime.h>
#include <math.h>

#define NB 32
#define CC 1024
#define SS 784
#define DD 128
#define KK 64
#define OUTD 1024
#define KD 8192          // K*D
#define VSPLIT 8         // split-K for vlad GEMM (784 = 8*98)
#define PSPLIT 16        // split-K for projection (8192 = 16*512)

// workspace layout (floats)
#define WS_XN     0                           // (N,D,S) normalized descriptors
#define WS_SA     (WS_XN + NB*DD*SS)          // (N,K,S) soft assign
#define WS_VLADP  (WS_SA + NB*KK*SS)          // (N,VSPLIT,K*D) vlad partials
#define WS_SASUMP (WS_VLADP + NB*VSPLIT*KD)   // (N,VSPLIT,K) sasum partials
#define WS_VLADN  (WS_SASUMP + NB*VSPLIT*KK)  // (N,K*D) normalized vlad
#define WS_OUTP   (WS_VLADN + NB*KD)          // (PSPLIT,N,OUT) proj partials

typedef __attribute__((ext_vector_type(8))) short bf16x8;   // 8 bf16 = 4 VGPRs
typedef __attribute__((ext_vector_type(4))) float f32x4;

// round-to-nearest-even fp32 -> bf16, packed pair
__device__ __forceinline__ unsigned int pk_bf16(float a, float b) {
    unsigned int ua = __builtin_bit_cast(unsigned int, a);
    unsigned int ub = __builtin_bit_cast(unsigned int, b);
    ua += 0x7FFFu + ((ua >> 16) & 1u);
    ub += 0x7FFFu + ((ub >> 16) & 1u);
    return (ua >> 16) | (ub & 0xFFFF0000u);
}

// ---------------------------------------------------------------------------
// Kernel A (MFMA): xf = Wpool @ x_n + bpool, L2-normalize over D (axis=1).
// Block tile 128d x 64s, 4 waves as 2(m) x 2(n), each wave 64d x 32s
// = 4 mt x 2 nt MFMAs of 16x16x32 bf16.  grid (13, N).
// LDS holds A/B tiles in MFMA *fragment order*: fragment f of tile mt lives
// at [mt*64 + lane]*16B, so ds_read_b128/ds_write_b128 are evenly spread
// across banks (minimum 8 cyc/wave, no conflict penalty).
// ---------------------------------------------------------------------------
__global__ __launch_bounds__(256)
void pool_norm_mfma(const float* __restrict__ x, const float* __restrict__ Wpool,
                    const float* __restrict__ bpool, float* __restrict__ xn)
{
    const int n    = blockIdx.y;
    const int s0   = blockIdx.x * 64;
    const int t    = threadIdx.x;
    const int l    = t & 63;
    const int w    = t >> 6;
    const int wm   = w & 1;        // d-half (64)
    const int wn   = w >> 1;       // s-half (32)
    const int lm   = l & 15;
    const int quad = l >> 4;

    __shared__ alignas(16) unsigned short As[8 * 64 * 8];  // 8 KB: 8 mt fragments
    __shared__ alignas(16) unsigned short Bs[4 * 64 * 8];  // 4 KB: 4 nt fragments
    __shared__ float bias[DD];
    __shared__ float red[2][64];

    if (t < DD) bias[t] = bpool[t];

    f32x4 acc[4][2];
#pragma unroll
    for (int i = 0; i < 4; i++)
#pragma unroll
        for (int j = 0; j < 2; j++) acc[i][j] = (f32x4){0.f, 0.f, 0.f, 0.f};

    const float* xptr = x + (size_t)n * CC * SS;

    // staging coords (constant over K loop)
    const int a_d  = t & 127;      // Wpool row for both passes
    const int a_q0 = t >> 7;       // quad 0/1; pass 1 adds 2
    const int b_s  = t & 63;       // s-local
    const int b_q  = t >> 6;       // quad for B

    for (int kk = 0; kk < CC; kk += 32) {
        // ---- A staging: 2 fragments/thread, each = Wpool[d][kk+q*8 .. +7]
#pragma unroll
        for (int p = 0; p < 2; p++) {
            const int q = a_q0 + 2 * p;
            const float4 v0 = *(const float4*)&Wpool[(size_t)a_d * CC + kk + q * 8];
            const float4 v1 = *(const float4*)&Wpool[(size_t)a_d * CC + kk + q * 8 + 4];
            const int mt = a_d >> 4, m = a_d & 15;
            unsigned int* dst = (unsigned int*)&As[(size_t)(mt * 64 + q * 16 + m) * 8];
            dst[0] = pk_bf16(v0.x, v0.y);
            dst[1] = pk_bf16(v0.z, v0.w);
            dst[2] = pk_bf16(v1.x, v1.y);
            dst[3] = pk_bf16(v1.z, v1.w);
        }
        // ---- B staging: 1 fragment/thread = x[kk+b_q*8 .. +7][s0+b_s]
        {
            const int s = s0 + b_s;
            float v[8];
#pragma unroll
            for (int u = 0; u < 8; u++) {
                const int c = kk + b_q * 8 + u;
                v[u] = (s < SS) ? xptr[(size_t)c * SS + s] : 0.f;
            }
            const int nt = b_s >> 4, nn = b_s & 15;
            unsigned int* dst = (unsigned int*)&Bs[(size_t)(nt * 64 + b_q * 16 + nn) * 8];
            dst[0] = pk_bf16(v[0], v[1]);
            dst[1] = pk_bf16(v[2], v[3]);
            dst[2] = pk_bf16(v[4], v[5]);
            dst[3] = pk_bf16(v[6], v[7]);
        }
        __syncthreads();
        // ---- MFMA: wave tile 4 mt x 2 nt
        bf16x8 bfrag[2];
#pragma unroll
        for (int j = 0; j < 2; j++) {
            const int nt = wn * 2 + j;
            bfrag[j] = *(const bf16x8*)&Bs[(size_t)(nt * 64 + l) * 8];
        }
#pragma unroll
        for (int i = 0; i < 4; i++) {
            const int mt = wm * 4 + i;
            const bf16x8 afrag = *(const bf16x8*)&As[(size_t)(mt * 64 + l) * 8];
#pragma unroll
            for (int j = 0; j < 2; j++)
                acc[i][j] = __builtin_amdgcn_mfma_f32_16x16x32_bf16(afrag, bfrag[j], acc[i][j], 0, 0, 0);
        }
        __syncthreads();
    }

    // ---- epilogue: +bias, sum-of-squares over d per s, L2 scale, store
    // D layout: d = (wm*4+i)*16 + quad*4 + r ; s_local = wn*32 + j*16 + lm
    float ssq[2] = {0.f, 0.f};
#pragma unroll
    for (int i = 0; i < 4; i++) {
#pragma unroll
        for (int r = 0; r < 4; r++) {
            const float bv = bias[(wm * 4 + i) * 16 + quad * 4 + r];
#pragma unroll
            for (int j = 0; j < 2; j++) {
                acc[i][j][r] += bv;
                ssq[j] += acc[i][j][r] * acc[i][j][r];
            }
        }
    }
    // reduce over quad (lanes lm, lm+16, lm+32, lm+48)
#pragma unroll
    for (int j = 0; j < 2; j++) {
        ssq[j] += __shfl_xor(ssq[j], 16, 64);
        ssq[j] += __shfl_xor(ssq[j], 32, 64);
    }
    if (quad == 0) {
        red[wm][wn * 32 + 0 * 16 + lm] = ssq[0];
        red[wm][wn * 32 + 1 * 16 + lm] = ssq[1];
    }
    __syncthreads();

    float* xnp = xn + (size_t)n * DD * SS;
#pragma unroll
    for (int j = 0; j < 2; j++) {
        const int sl = wn * 32 + j * 16 + lm;
        const float scale = 1.f / fmaxf(sqrtf(red[0][sl] + red[1][sl]), 1e-12f);
        const int s = s0 + sl;
        if (s < SS) {
#pragma unroll
            for (int i = 0; i < 4; i++) {
#pragma unroll
                for (int r = 0; r < 4; r++) {
                    const int d = (wm * 4 + i) * 16 + quad * 4 + r;
                    xnp[(size_t)d * SS + s] = acc[i][j][r] * scale;
                }
            }
        }
    }
}

// ---------------------------------------------------------------------------
// Kernel C: sa = softmax_k(Wconv @ xn + bconv).  One thread per s.
// grid (ceil(S/256)=4, N), block 256.  Wconv (64x128) cached in LDS.
// ---------------------------------------------------------------------------
__global__ __launch_bounds__(256)
void assign_softmax_kernel(const float* __restrict__ xn, const float* __restrict__ Wconv,
                           const float* __restrict__ bconv, float* __restrict__ sa)
{
    __shared__ float Wc[KK * DD];   // 32 KB
    __shared__ float bcs[KK];
    const int t = threadIdx.x;
#pragma unroll
    for (int i = 0; i < 32; i++) Wc[t + 256 * i] = Wconv[t + 256 * i];
    if (t < KK) bcs[t] = bconv[t];
    __syncthreads();

    const int n = blockIdx.y;
    const int s = blockIdx.x * 256 + t;
    if (s >= SS) return;

    float acc[KK];
#pragma unroll
    for (int k = 0; k < KK; k++) acc[k] = bcs[k];

    const float* xp = xn + (size_t)n * DD * SS + s;
    for (int d0 = 0; d0 < DD; d0 += 8) {
        float xv[8];
#pragma unroll
        for (int dd = 0; dd < 8; dd++) xv[dd] = xp[(d0 + dd) * SS];
#pragma unroll
        for (int k = 0; k < KK; k++) {
            const float4 w0 = *(const float4*)&Wc[k * DD + d0];
            const float4 w1 = *(const float4*)&Wc[k * DD + d0 + 4];
            acc[k] += w0.x * xv[0] + w0.y * xv[1] + w0.z * xv[2] + w0.w * xv[3]
                    + w1.x * xv[4] + w1.y * xv[5] + w1.z * xv[6] + w1.w * xv[7];
        }
    }

    float m = -1e30f;
#pragma unroll
    for (int k = 0; k < KK; k++) m = fmaxf(m, acc[k]);
    float sum = 0.f;
#pragma unroll
    for (int k = 0; k < KK; k++) { acc[k] = expf(acc[k] - m); sum += acc[k]; }
    const float r = 1.f / sum;
    float* sap = sa + ((size_t)n * KK) * SS + s;
#pragma unroll
    for (int k = 0; k < KK; k++) sap[k * SS] = acc[k] * r;
}

// ---------------------------------------------------------------------------
// Kernel D: vlad partial GEMM: vladp[n,sp,k,d] = sum_{s in range} sa[k,s]*xn[d,s]
// plus partial sasum.  grid (VSPLIT, N), block 256, s-range = 98 each.
// ---------------------------------------------------------------------------
__global__ __launch_bounds__(256)
void vlad_partial_kernel(const float* __restrict__ xn, const float* __restrict__ sa,
                         float* __restrict__ vladp, float* __restrict__ sasump)
{
    const int sp = blockIdx.x;
    const int n  = blockIdx.y;
    const int t  = threadIdx.x;
    const int tx = t & 15;   // d = tx + 16*i
    const int ty = t >> 4;   // k = ty + 16*j

    __shared__ float XnS[DD][33];
    __shared__ float SaS[KK][33];

    float acc[4][8];
#pragma unroll
    for (int j = 0; j < 4; j++)
#pragma unroll
        for (int i = 0; i < 8; i++) acc[j][i] = 0.f;
    float local_sasum = 0.f;

    const int s_begin = sp * 98;
    const float* xp = xn + (size_t)n * DD * SS;
    const float* sp_ = sa + (size_t)n * KK * SS;

    for (int ch = 0; ch < 4; ch++) {           // 4 chunks of 32 cover 98 (last partial)
        const int sb = s_begin + ch * 32;
        {
            const int si = t & 31, dl = t >> 5;
#pragma unroll
            for (int i = 0; i < 16; i++) {
                const int d = dl + 8 * i;
                const int s = sb + si;
                XnS[d][si] = (s < s_begin + 98) ? xp[d * SS + s] : 0.f;
            }
#pragma unroll
            for (int i = 0; i < 8; i++) {
                const int k = dl + 8 * i;
                const int s = sb + si;
                SaS[k][si] = (s < s_begin + 98) ? sp_[k * SS + s] : 0.f;
            }
        }
        __syncthreads();
        if (t < KK) {
#pragma unroll
            for (int si = 0; si < 32; si++) local_sasum += SaS[t][si];
        }
#pragma unroll
        for (int si = 0; si < 32; si++) {
            float a[4], b[8];
#pragma unroll
            for (int j = 0; j < 4; j++) a[j] = SaS[ty + 16 * j][si];
#pragma unroll
            for (int i = 0; i < 8; i++) b[i] = XnS[tx + 16 * i][si];
#pragma unroll
            for (int j = 0; j < 4; j++)
#pragma unroll
                for (int i = 0; i < 8; i++) acc[j][i] += a[j] * b[i];
        }
        __syncthreads();
    }

    float* vp = vladp + ((size_t)n * VSPLIT + sp) * KD;
#pragma unroll
    for (int j = 0; j < 4; j++)
#pragma unroll
        for (int i = 0; i < 8; i++)
            vp[(ty + 16 * j) * DD + (tx + 16 * i)] = acc[j][i];
    if (t < KK) sasump[((size_t)n * VSPLIT + sp) * KK + t] = local_sasum;
}

// ---------------------------------------------------------------------------
// Kernel D2: reduce partials, subtract centroids*sasum, L2-norm over k (axis=1),
// write vladn (N, K*D).  grid (N), block 256: thread owns d=t&127, k-half t>>7.
// ---------------------------------------------------------------------------
__global__ __launch_bounds__(256)
void vlad_finish_kernel(const float* __restrict__ vladp, const float* __restrict__ sasump,
                        const float* __restrict__ centroids, float* __restrict__ vladn)
{
    const int n = blockIdx.x;
    const int t = threadIdx.x;
    const int d = t & 127;
    const int kh = t >> 7;   // 0/1: k = kh*32 + j

    __shared__ float sas[KK];
    __shared__ float red2[2][128];

    if (t < KK) {
        float ssum = 0.f;
#pragma unroll
        for (int p = 0; p < VSPLIT; p++) ssum += sasump[((size_t)n * VSPLIT + p) * KK + t];
        sas[t] = ssum;
    }
    __syncthreads();

    float v[32];
    float ssp = 0.f;
#pragma unroll
    for (int j = 0; j < 32; j++) {
        const int k = kh * 32 + j;
        float a = 0.f;
#pragma unroll
        for (int p = 0; p < VSPLIT; p++)
            a += vladp[((size_t)n * VSPLIT + p) * KD + k * DD + d];
        a -= centroids[k * DD + d] * sas[k];
        v[j] = a;
        ssp += a * a;
    }
    red2[kh][d] = ssp;
    __syncthreads();
    const float scale = 1.f / fmaxf(sqrtf(red2[0][d] + red2[1][d]), 1e-12f);

    float* vo = vladn + (size_t)n * KD;
#pragma unroll
    for (int j = 0; j < 32; j++) {
        const int k = kh * 32 + j;
        vo[k * DD + d] = v[j] * scale;
    }
}

// ---------------------------------------------------------------------------
// Kernel F: projection partials: outp[p,n,o] = vladn[n, c-range] . Wproj[o, c-range]
// grid (OUT/64=16, PSPLIT=16), block 256.
// ---------------------------------------------------------------------------
__global__ __launch_bounds__(256)
void proj_partial_kernel(const float* __restrict__ vladn, const float* __restrict__ Wproj,
                         float* __restrict__ outp)
{
    const int o0 = blockIdx.x * 64;
    const int c0 = blockIdx.y * (KD / PSPLIT);   // 512-wide K slice
    const int t  = threadIdx.x;
    const int ow = t & 31;   // o = o0 + ow + 32*i
    const int nw = t >> 5;   // n = nw + 8*j

    __shared__ float Ws[64][33];
    __shared__ float Vs[32][33];

    float acc[2][4];
#pragma unroll
    for (int i = 0; i < 2; i++)
#pragma unroll
        for (int j = 0; j < 4; j++) acc[i][j] = 0.f;

    for (int cc0 = c0; cc0 < c0 + KD / PSPLIT; cc0 += 32) {
        {
            const int col = t & 31, row = t >> 5;
#pragma unroll
            for (int i = 0; i < 8; i++)
                Ws[row + 8 * i][col] = Wproj[(size_t)(o0 + row + 8 * i) * KD + cc0 + col];
#pragma unroll
            for (int i = 0; i < 4; i++)
                Vs[row + 8 * i][col] = vladn[(size_t)(row + 8 * i) * KD + cc0 + col];
        }
        __syncthreads();
#pragma unroll
        for (int cc = 0; cc < 32; cc++) {
            float wv[2], vv[4];
#pragma unroll
            for (int i = 0; i < 2; i++) wv[i] = Ws[ow + 32 * i][cc];
#pragma unroll
            for (int j = 0; j < 4; j++) vv[j] = Vs[nw + 8 * j][cc];
#pragma unroll
            for (int i = 0; i < 2; i++)
#pragma unroll
                for (int j = 0; j < 4; j++) acc[i][j] += wv[i] * vv[j];
        }
        __syncthreads();
    }

#pragma unroll
    for (int i = 0; i < 2; i++)
#pragma unroll
        for (int j = 0; j < 4; j++) {
            const int o = o0 + ow + 32 * i;
            const int n = nw + 8 * j;
            outp[((size_t)blockIdx.y * NB + n) * OUTD + o] = acc[i][j];
        }
}

// ---------------------------------------------------------------------------
// Kernel G: sum projection partials + bproj, final L2 norm over OUT, write d_out.
// grid (N), block 256; thread handles o = t + 256*i.
// ---------------------------------------------------------------------------
__global__ __launch_bounds__(256)
void final_norm_kernel(const float* __restrict__ outp, const float* __restrict__ bproj,
                       float* __restrict__ out)
{
    const int n = blockIdx.x;
    const int t = threadIdx.x;

    float v[4];
    float ssp = 0.f;
#pragma unroll
    for (int i = 0; i < 4; i++) {
        const int o = t + 256 * i;
        float a = 0.f;
#pragma unroll
        for (int p = 0; p < PSPLIT; p++) a += outp[((size_t)p * NB + n) * OUTD + o];
        a += bproj[o];
        v[i] = a;
        ssp += a * a;
    }

    // wave reduce then cross-wave via LDS
#pragma unroll
    for (int off = 32; off > 0; off >>= 1) ssp += __shfl_down(ssp, off, 64);
    __shared__ float rs[4];
    if ((t & 63) == 0) rs[t >> 6] = ssp;
    __syncthreads();
    const float total = rs[0] + rs[1] + rs[2] + rs[3];
    const float scale = 1.f / fmaxf(sqrtf(total), 1e-12f);

#pragma unroll
    for (int i = 0; i < 4; i++) out[(size_t)n * OUTD + t + 256 * i] = v[i] * scale;
}

// ---------------------------------------------------------------------------
extern "C" void kernel_launch(void* const* d_in, const int* in_sizes, int n_in,
                              void* d_out, int out_size, void* d_ws, size_t ws_size,
                              hipStream_t stream)
{
    const float* x         = (const float*)d_in[0];
    const float* Wpool     = (const float*)d_in[1];
    const float* bpool     = (const float*)d_in[2];
    const float* Wconv     = (const float*)d_in[3];
    const float* bconv     = (const float*)d_in[4];
    const float* centroids = (const float*)d_in[5];
    const float* Wproj     = (const float*)d_in[6];
    const float* bproj     = (const float*)d_in[7];
    float* out = (float*)d_out;
    float* ws  = (float*)d_ws;

    float* xn     = ws + WS_XN;
    float* sa     = ws + WS_SA;
    float* vladp  = ws + WS_VLADP;
    float* sasump = ws + WS_SASUMP;
    float* vladn  = ws + WS_VLADN;
    float* outp   = ws + WS_OUTP;

    pool_norm_mfma<<<dim3(13, NB), 256, 0, stream>>>(x, Wpool, bpool, xn);
    assign_softmax_kernel<<<dim3(4, NB), 256, 0, stream>>>(xn, Wconv, bconv, sa);
    vlad_partial_kernel<<<dim3(VSPLIT, NB), 256, 0, stream>>>(xn, sa, vladp, sasump);
    vlad_finish_kernel<<<dim3(NB), 256, 0, stream>>>(vladp, sasump, centroids, vladn);
    proj_partial_kernel<<<dim3(OUTD / 64, PSPLIT), 256, 0, stream>>>(vladn, Wproj, outp);
    final_norm_kernel<<<dim3(NB), 256, 0, stream>>>(outp, bproj, out);
}

// Round 3
// 273.248 us; speedup vs baseline: 1.9234x; 1.2490x over previous
//
#include <hip/hip_runtime.h>
#include <math.h>

#define NB 32
#define CC 1024
#define SS 784
#define SP 832           // padded S (26*32), pad region holds zeros
#define DD 128
#define KK 64
#define OUTD 1024
#define KD 8192          // K*D
#define NSPLIT 13        // vlad s-splits (64 s each)
#define PSPLIT 16        // split-K for projection (8192 = 16*512)

// workspace layout (BYTE offsets)
#define OFF_XN    0                                  // bf16 (N,D,SP)
#define OFF_SA    (OFF_XN + NB*DD*SP*2)              // bf16 (N,K,SP)
#define OFF_VLADP (OFF_SA + NB*KK*SP*2)              // f32 (N,NSPLIT,K*D)
#define OFF_SASUM (OFF_VLADP + NB*NSPLIT*KD*4)       // f32 (N,NSPLIT,K)
#define OFF_VLADN (OFF_SASUM + NB*NSPLIT*KK*4)       // f32 (N,K*D)
#define OFF_OUTP  (OFF_VLADN + NB*KD*4)              // f32 (PSPLIT,N,OUT)
// total = 27,107,328 B < 30.87 MB used by the (accepted) round-1 layout

typedef __attribute__((ext_vector_type(8))) short bf16x8;   // 8 bf16 = 4 VGPRs
typedef __attribute__((ext_vector_type(4))) float f32x4;

// round-to-nearest-even fp32 -> bf16, packed pair
__device__ __forceinline__ unsigned int pk_bf16(float a, float b) {
    unsigned int ua = __builtin_bit_cast(unsigned int, a);
    unsigned int ub = __builtin_bit_cast(unsigned int, b);
    ua += 0x7FFFu + ((ua >> 16) & 1u);
    ub += 0x7FFFu + ((ub >> 16) & 1u);
    return (ua >> 16) | (ub & 0xFFFF0000u);
}
__device__ __forceinline__ unsigned short f2bf(float a) {
    unsigned int ua = __builtin_bit_cast(unsigned int, a);
    ua += 0x7FFFu + ((ua >> 16) & 1u);
    return (unsigned short)(ua >> 16);
}
__device__ __forceinline__ float bf2f(unsigned short u) {
    unsigned int v = ((unsigned int)u) << 16;
    return __builtin_bit_cast(float, v);
}

// ---------------------------------------------------------------------------
// Fused Kernel: pool GEMM (MFMA bf16) + bias + descriptor L2-norm + assign
// GEMM (MFMA) + softmax.  Outputs xn (bf16 [d][SP]) and sa (bf16 [k][SP]),
// both laid out so the vlad kernel can load MFMA fragments straight from
// global memory as 16B loads.
// Block tile: 128 d x 32 s.  grid (26, N) = 832 blocks (~3.25/CU).
// K-loop is register-prefetch pipelined (load kk+32 while MFMA-ing kk).
// ---------------------------------------------------------------------------
__global__ __launch_bounds__(256)
void pool_assign_fused(const float* __restrict__ x, const float* __restrict__ Wpool,
                       const float* __restrict__ bpool, const float* __restrict__ Wconv,
                       const float* __restrict__ bconv,
                       unsigned short* __restrict__ xn, unsigned short* __restrict__ sa)
{
    const int n  = blockIdx.y;
    const int s0 = blockIdx.x * 32;
    const int t  = threadIdx.x;
    const int l  = t & 63;
    const int w  = t >> 6;
    const int wm = w & 1;        // d-half (64) for pool phase
    const int wn = w >> 1;       // s-half (16) for pool phase
    const int lm = l & 15;
    const int quad = l >> 4;

    __shared__ alignas(16) unsigned short As[8 * 64 * 8];   // 8 KB  (Wpool frags)
    __shared__ alignas(16) unsigned short Bs[2 * 64 * 8];   // 2 KB  (x frags)
    __shared__ alignas(16) unsigned short Wc[16 * 64 * 8];  // 16 KB (Wconv frags)
    __shared__ alignas(16) unsigned short xnT[32][136];     // 8.5 KB [s][d] pad->2-way
    __shared__ float bias[DD];
    __shared__ float bcv[KK];
    __shared__ float red[2][32];
    __shared__ float sums[2][2][16];

    // ---- Wconv -> LDS as A-operand fragments (tile = kt*4+ds), once
#pragma unroll
    for (int f = 0; f < 4; f++) {
        const int idx  = t + 256 * f;          // 0..1023 fragment-lanes
        const int tile = idx >> 6, ln = idx & 63;
        const int k = (tile >> 2) * 16 + (ln & 15);
        const int d = (tile & 3) * 32 + (ln >> 4) * 8;
        const float4 v0 = *(const float4*)&Wconv[k * DD + d];
        const float4 v1 = *(const float4*)&Wconv[k * DD + d + 4];
        unsigned int* dst = (unsigned int*)&Wc[(size_t)(tile * 64 + ln) * 8];
        dst[0] = pk_bf16(v0.x, v0.y); dst[1] = pk_bf16(v0.z, v0.w);
        dst[2] = pk_bf16(v1.x, v1.y); dst[3] = pk_bf16(v1.z, v1.w);
    }
    if (t < DD) bias[t] = bpool[t];
    if (t < KK) bcv[t]  = bconv[t];

    f32x4 acc[4];
#pragma unroll
    for (int i = 0; i < 4; i++) acc[i] = (f32x4){0.f, 0.f, 0.f, 0.f};

    const float* xptr = x + (size_t)n * CC * SS;
    const int a_d  = t & 127;    // Wpool row
    const int aq0  = t >> 7;     // handles k-octets aq0 and aq0+2
    const int b_s  = t & 31;     // s-local
    const int b_cg = t >> 5;     // 4-c group (0..7)
    const int gs   = s0 + b_s;
    const bool bvalid = gs < SS;

    float4 ra0, ra1, ra2, ra3;
    float  rb[4] = {0.f, 0.f, 0.f, 0.f};

#define LOAD_TILE(KKv)                                                            \
    {   const int kkL = (KKv);                                                    \
        const float* wp = &Wpool[(size_t)a_d * CC + kkL];                         \
        ra0 = *(const float4*)(wp + aq0 * 8);                                     \
        ra1 = *(const float4*)(wp + aq0 * 8 + 4);                                 \
        ra2 = *(const float4*)(wp + (aq0 + 2) * 8);                               \
        ra3 = *(const float4*)(wp + (aq0 + 2) * 8 + 4);                           \
        if (bvalid) {                                                             \
            const float* bp = xptr + (size_t)(kkL + b_cg * 4) * SS + gs;          \
            rb[0] = bp[0]; rb[1] = bp[SS]; rb[2] = bp[2 * SS]; rb[3] = bp[3 * SS];\
        }                                                                         \
    }

#define PACK_TILE                                                                             \
    {   unsigned int* d1 = (unsigned int*)&As[(size_t)((a_d >> 4) * 64 + aq0 * 16 + (a_d & 15)) * 8];       \
        d1[0] = pk_bf16(ra0.x, ra0.y); d1[1] = pk_bf16(ra0.z, ra0.w);                          \
        d1[2] = pk_bf16(ra1.x, ra1.y); d1[3] = pk_bf16(ra1.z, ra1.w);                          \
        unsigned int* d2 = (unsigned int*)&As[(size_t)((a_d >> 4) * 64 + (aq0 + 2) * 16 + (a_d & 15)) * 8]; \
        d2[0] = pk_bf16(ra2.x, ra2.y); d2[1] = pk_bf16(ra2.z, ra2.w);                          \
        d2[2] = pk_bf16(ra3.x, ra3.y); d2[3] = pk_bf16(ra3.z, ra3.w);                          \
        unsigned int* db = (unsigned int*)&Bs[(size_t)((b_s >> 4) * 64 + (b_cg >> 1) * 16 + (b_s & 15)) * 8]; \
        db[(b_cg & 1) * 2]     = pk_bf16(rb[0], rb[1]);                                        \
        db[(b_cg & 1) * 2 + 1] = pk_bf16(rb[2], rb[3]);                                        \
    }

    LOAD_TILE(0);
    for (int kk = 0; kk < CC; kk += 32) {
        PACK_TILE;
        __syncthreads();
        if (kk + 32 < CC) LOAD_TILE(kk + 32);    // prefetch; vmcnt waited at next PACK
        const bf16x8 bfrag = *(const bf16x8*)&Bs[(size_t)(wn * 64 + l) * 8];
#pragma unroll
        for (int i = 0; i < 4; i++) {
            const bf16x8 afrag = *(const bf16x8*)&As[(size_t)((wm * 4 + i) * 64 + l) * 8];
            acc[i] = __builtin_amdgcn_mfma_f32_16x16x32_bf16(afrag, bfrag, acc[i], 0, 0, 0);
        }
        __syncthreads();
    }

    // ---- pool epilogue: bias, L2-norm over d (C layout: d=(wm*4+i)*16+quad*4+r, s=wn*16+lm)
    float ssq = 0.f;
#pragma unroll
    for (int i = 0; i < 4; i++) {
#pragma unroll
        for (int r = 0; r < 4; r++) {
            acc[i][r] += bias[(wm * 4 + i) * 16 + quad * 4 + r];
            ssq += acc[i][r] * acc[i][r];
        }
    }
    ssq += __shfl_xor(ssq, 16, 64);
    ssq += __shfl_xor(ssq, 32, 64);
    if (quad == 0) red[wm][wn * 16 + lm] = ssq;
    __syncthreads();
    const int sl = wn * 16 + lm;
    const float scale = 1.f / fmaxf(sqrtf(red[0][sl] + red[1][sl]), 1e-12f);
    const int s = s0 + sl;
    unsigned short* xnp = xn + (size_t)n * DD * SP;
#pragma unroll
    for (int i = 0; i < 4; i++) {
        const float v0 = acc[i][0] * scale, v1 = acc[i][1] * scale;
        const float v2 = acc[i][2] * scale, v3 = acc[i][3] * scale;
        const int dbase = (wm * 4 + i) * 16 + quad * 4;
        unsigned int* pT = (unsigned int*)&xnT[sl][dbase];
        pT[0] = pk_bf16(v0, v1);
        pT[1] = pk_bf16(v2, v3);
        xnp[(size_t)(dbase + 0) * SP + s] = f2bf(v0);   // pad s>=SS: acc==0 -> stores 0
        xnp[(size_t)(dbase + 1) * SP + s] = f2bf(v1);
        xnp[(size_t)(dbase + 2) * SP + s] = f2bf(v2);
        xnp[(size_t)(dbase + 3) * SP + s] = f2bf(v3);
    }
    __syncthreads();

    // ---- assign GEMM: logits[64k x 32s] = Wconv(bf16) @ xnT, K=128 in 4 steps
    const int kth = w & 1;     // k-half (2 kt tiles)
    const int ntA = w >> 1;    // s-half (16)
    f32x4 acc2[2];
    acc2[0] = (f32x4){0.f, 0.f, 0.f, 0.f};
    acc2[1] = (f32x4){0.f, 0.f, 0.f, 0.f};
#pragma unroll
    for (int dsv = 0; dsv < 4; dsv++) {
        const bf16x8 bfrag = *(const bf16x8*)&xnT[ntA * 16 + lm][dsv * 32 + quad * 8];
#pragma unroll
        for (int j = 0; j < 2; j++) {
            const int kt = kth * 2 + j;
            const bf16x8 afrag = *(const bf16x8*)&Wc[(size_t)((kt * 4 + dsv) * 64 + l) * 8];
            acc2[j] = __builtin_amdgcn_mfma_f32_16x16x32_bf16(afrag, bfrag, acc2[j], 0, 0, 0);
        }
    }
    // ---- softmax over k (no max-subtraction needed: |logits| <= ~1.3)
    float ex[2][4]; float psum = 0.f;
#pragma unroll
    for (int j = 0; j < 2; j++)
#pragma unroll
        for (int r = 0; r < 4; r++) {
            const int k = (kth * 2 + j) * 16 + quad * 4 + r;
            const float e = expf(acc2[j][r] + bcv[k]);
            ex[j][r] = e; psum += e;
        }
    psum += __shfl_xor(psum, 16, 64);
    psum += __shfl_xor(psum, 32, 64);
    if (quad == 0) sums[kth][ntA][lm] = psum;
    __syncthreads();
    const float inv = 1.f / (sums[0][ntA][lm] + sums[1][ntA][lm]);
    const int s2 = s0 + ntA * 16 + lm;
    const bool val2 = s2 < SS;
    unsigned short* sap = sa + (size_t)n * KK * SP;
#pragma unroll
    for (int j = 0; j < 2; j++)
#pragma unroll
        for (int r = 0; r < 4; r++) {
            const int k = (kth * 2 + j) * 16 + quad * 4 + r;
            sap[(size_t)k * SP + s2] = val2 ? f2bf(ex[j][r] * inv) : (unsigned short)0;
        }
#undef LOAD_TILE
#undef PACK_TILE
}

// ---------------------------------------------------------------------------
// vlad GEMM (MFMA, fragment loads DIRECT from global, no LDS):
// vladp[n,p,k,d] = sum_{s in p-range(64)} sa[k,s]*xn[d,s]; plus sasum partials.
// grid (NSPLIT, N) = 416 blocks; wave tile 32k x 64d; 2 k-steps of 32.
// ---------------------------------------------------------------------------
__global__ __launch_bounds__(256)
void vlad_mfma(const unsigned short* __restrict__ xn, const unsigned short* __restrict__ sa,
               float* __restrict__ vladp, float* __restrict__ sasump)
{
    const int p = blockIdx.x;
    const int n = blockIdx.y;
    const int t = threadIdx.x;
    const int l = t & 63;
    const int w = t >> 6;
    const int kth = w & 1, nh = w >> 1;
    const int lm = l & 15, quad = l >> 4;

    const unsigned short* sap = sa + (size_t)n * KK * SP;
    const unsigned short* xnp = xn + (size_t)n * DD * SP;

    f32x4 acc[2][4];
#pragma unroll
    for (int j = 0; j < 2; j++)
#pragma unroll
        for (int i = 0; i < 4; i++) acc[j][i] = (f32x4){0.f, 0.f, 0.f, 0.f};

#pragma unroll
    for (int st = 0; st < 2; st++) {
        const int sb = p * 64 + st * 32 + quad * 8;
        bf16x8 af[2], bfv[4];
#pragma unroll
        for (int j = 0; j < 2; j++)
            af[j] = *(const bf16x8*)&sap[(size_t)((kth * 2 + j) * 16 + lm) * SP + sb];
#pragma unroll
        for (int i = 0; i < 4; i++)
            bfv[i] = *(const bf16x8*)&xnp[(size_t)((nh * 4 + i) * 16 + lm) * SP + sb];
#pragma unroll
        for (int j = 0; j < 2; j++)
#pragma unroll
            for (int i = 0; i < 4; i++)
                acc[j][i] = __builtin_amdgcn_mfma_f32_16x16x32_bf16(af[j], bfv[i], acc[j][i], 0, 0, 0);
    }

    float* vp = vladp + ((size_t)n * NSPLIT + p) * KD;
#pragma unroll
    for (int j = 0; j < 2; j++)
#pragma unroll
        for (int i = 0; i < 4; i++)
#pragma unroll
            for (int r = 0; r < 4; r++) {
                const int k = (kth * 2 + j) * 16 + quad * 4 + r;
                const int d = (nh * 4 + i) * 16 + lm;
                vp[(size_t)k * DD + d] = acc[j][i][r];
            }

    if (t < KK) {
        float sm = 0.f;
        const unsigned short* rp = &sap[(size_t)t * SP + p * 64];
#pragma unroll
        for (int c = 0; c < 64; c++) sm += bf2f(rp[c]);
        sasump[((size_t)n * NSPLIT + p) * KK + t] = sm;
    }
}

// ---------------------------------------------------------------------------
// vlad finish: reduce NSPLIT partials, subtract centroids*sasum, L2-norm over
// k, write vladn (N, K*D) fp32.  grid (4 d-groups, N) = 128 blocks.
// thread: d = dg*32 + (t&31), k-group kg = t>>5 (8 k each).
// ---------------------------------------------------------------------------
__global__ __launch_bounds__(256)
void vlad_finish(const float* __restrict__ vladp, const float* __restrict__ sasump,
                 const float* __restrict__ centroids, float* __restrict__ vladn)
{
    const int dg = blockIdx.x;
    const int n  = blockIdx.y;
    const int t  = threadIdx.x;
    const int d  = dg * 32 + (t & 31);
    const int kg = t >> 5;

    __shared__ float sas[KK];
    __shared__ float red[8][32];

    if (t < KK) {
        float sm = 0.f;
#pragma unroll
        for (int p = 0; p < NSPLIT; p++) sm += sasump[((size_t)n * NSPLIT + p) * KK + t];
        sas[t] = sm;
    }
    __syncthreads();

    float v[8]; float ssq = 0.f;
#pragma unroll
    for (int j = 0; j < 8; j++) {
        const int k = kg * 8 + j;
        float a = 0.f;
#pragma unroll
        for (int p = 0; p < NSPLIT; p++)
            a += vladp[((size_t)n * NSPLIT + p) * KD + (size_t)k * DD + d];
        a -= centroids[(size_t)k * DD + d] * sas[k];
        v[j] = a; ssq += a * a;
    }
    red[kg][t & 31] = ssq;
    __syncthreads();
    float tot = 0.f;
#pragma unroll
    for (int g = 0; g < 8; g++) tot += red[g][t & 31];
    const float scale = 1.f / fmaxf(sqrtf(tot), 1e-12f);
    float* vo = vladn + (size_t)n * KD;
#pragma unroll
    for (int j = 0; j < 8; j++) vo[(size_t)(kg * 8 + j) * DD + d] = v[j] * scale;
}

// ---------------------------------------------------------------------------
// projection partials: outp[p,n,o] = vladn[n, c-slice] . Wproj[o, c-slice]
// grid (OUT/64=16, PSPLIT=16) = 256 blocks; float4 global loads + register
// prefetch pipeline.
// ---------------------------------------------------------------------------
__global__ __launch_bounds__(256)
void proj_partial_kernel(const float* __restrict__ vladn, const float* __restrict__ Wproj,
                         float* __restrict__ outp)
{
    const int o0 = blockIdx.x * 64;
    const int c0 = blockIdx.y * (KD / PSPLIT);
    const int t  = threadIdx.x;
    const int ow = t & 31, nw = t >> 5;
    const int wr = t & 63, wq = t >> 6;   // Ws staging: row, col-quarter (8 c)
    const int vr = t & 31, vq = t >> 5;   // Vs staging: row, col-eighth (4 c)

    __shared__ float Ws[64][33];
    __shared__ float Vs[32][33];

    float acc[2][4];
#pragma unroll
    for (int i = 0; i < 2; i++)
#pragma unroll
        for (int j = 0; j < 4; j++) acc[i][j] = 0.f;

    float4 w0 = *(const float4*)&Wproj[(size_t)(o0 + wr) * KD + c0 + wq * 8];
    float4 w1 = *(const float4*)&Wproj[(size_t)(o0 + wr) * KD + c0 + wq * 8 + 4];
    float4 v4 = *(const float4*)&vladn[(size_t)vr * KD + c0 + vq * 4];

    for (int cc0 = c0; cc0 < c0 + KD / PSPLIT; cc0 += 32) {
        Ws[wr][wq * 8 + 0] = w0.x; Ws[wr][wq * 8 + 1] = w0.y;
        Ws[wr][wq * 8 + 2] = w0.z; Ws[wr][wq * 8 + 3] = w0.w;
        Ws[wr][wq * 8 + 4] = w1.x; Ws[wr][wq * 8 + 5] = w1.y;
        Ws[wr][wq * 8 + 6] = w1.z; Ws[wr][wq * 8 + 7] = w1.w;
        Vs[vr][vq * 4 + 0] = v4.x; Vs[vr][vq * 4 + 1] = v4.y;
        Vs[vr][vq * 4 + 2] = v4.z; Vs[vr][vq * 4 + 3] = v4.w;
        __syncthreads();
        if (cc0 + 32 < c0 + KD / PSPLIT) {
            w0 = *(const float4*)&Wproj[(size_t)(o0 + wr) * KD + cc0 + 32 + wq * 8];
            w1 = *(const float4*)&Wproj[(size_t)(o0 + wr) * KD + cc0 + 32 + wq * 8 + 4];
            v4 = *(const float4*)&vladn[(size_t)vr * KD + cc0 + 32 + vq * 4];
        }
#pragma unroll
        for (int cc = 0; cc < 32; cc++) {
            float wv[2], vv[4];
            wv[0] = Ws[ow][cc]; wv[1] = Ws[ow + 32][cc];
#pragma unroll
            for (int j = 0; j < 4; j++) vv[j] = Vs[nw + 8 * j][cc];
#pragma unroll
            for (int i = 0; i < 2; i++)
#pragma unroll
                for (int j = 0; j < 4; j++) acc[i][j] += wv[i] * vv[j];
        }
        __syncthreads();
    }

#pragma unroll
    for (int i = 0; i < 2; i++)
#pragma unroll
        for (int j = 0; j < 4; j++) {
            const int o = o0 + ow + 32 * i;
            const int nn = nw + 8 * j;
            outp[((size_t)blockIdx.y * NB + nn) * OUTD + o] = acc[i][j];
        }
}

// ---------------------------------------------------------------------------
// final: sum projection partials + bproj, L2 norm over OUT, write d_out.
// ---------------------------------------------------------------------------
__global__ __launch_bounds__(256)
void final_norm_kernel(const float* __restrict__ outp, const float* __restrict__ bproj,
                       float* __restrict__ out)
{
    const int n = blockIdx.x;
    const int t = threadIdx.x;

    float v[4];
    float ssp = 0.f;
#pragma unroll
    for (int i = 0; i < 4; i++) {
        const int o = t + 256 * i;
        float a = 0.f;
#pragma unroll
        for (int p = 0; p < PSPLIT; p++) a += outp[((size_t)p * NB + n) * OUTD + o];
        a += bproj[o];
        v[i] = a;
        ssp += a * a;
    }
#pragma unroll
    for (int off = 32; off > 0; off >>= 1) ssp += __shfl_down(ssp, off, 64);
    __shared__ float rs[4];
    if ((t & 63) == 0) rs[t >> 6] = ssp;
    __syncthreads();
    const float total = rs[0] + rs[1] + rs[2] + rs[3];
    const float scale = 1.f / fmaxf(sqrtf(total), 1e-12f);
#pragma unroll
    for (int i = 0; i < 4; i++) out[(size_t)n * OUTD + t + 256 * i] = v[i] * scale;
}

// ---------------------------------------------------------------------------
extern "C" void kernel_launch(void* const* d_in, const int* in_sizes, int n_in,
                              void* d_out, int out_size, void* d_ws, size_t ws_size,
                              hipStream_t stream)
{
    const float* x         = (const float*)d_in[0];
    const float* Wpool     = (const float*)d_in[1];
    const float* bpool     = (const float*)d_in[2];
    const float* Wconv     = (const float*)d_in[3];
    const float* bconv     = (const float*)d_in[4];
    const float* centroids = (const float*)d_in[5];
    const float* Wproj     = (const float*)d_in[6];
    const float* bproj     = (const float*)d_in[7];
    float* out = (float*)d_out;
    char*  wsb = (char*)d_ws;

    unsigned short* xn     = (unsigned short*)(wsb + OFF_XN);
    unsigned short* sa     = (unsigned short*)(wsb + OFF_SA);
    float*          vladp  = (float*)(wsb + OFF_VLADP);
    float*          sasump = (float*)(wsb + OFF_SASUM);
    float*          vladn  = (float*)(wsb + OFF_VLADN);
    float*          outp   = (float*)(wsb + OFF_OUTP);

    pool_assign_fused<<<dim3(SP / 32, NB), 256, 0, stream>>>(x, Wpool, bpool, Wconv, bconv, xn, sa);
    vlad_mfma<<<dim3(NSPLIT, NB), 256, 0, stream>>>(xn, sa, vladp, sasump);
    vlad_finish<<<dim3(4, NB), 256, 0, stream>>>(vladp, sasump, centroids, vladn);
    proj_partial_kernel<<<dim3(OUTD / 64, PSPLIT), 256, 0, stream>>>(vladn, Wproj, outp);
    final_norm_kernel<<<dim3(NB), 256, 0, stream>>>(outp, bproj, out);
}

// Round 4
// 252.985 us; speedup vs baseline: 2.0774x; 1.0801x over previous
//
#include <hip/hip_runtime.h>
#include <math.h>

#define NB 32
#define CC 1024
#define SS 784
#define SP 832           // padded S (26*32); sa pad region is zeroed
#define DD 128
#define KK 64
#define OUTD 1024
#define KD 8192          // K*D
#define NSPLIT 13        // vlad s-splits (64 s each)
#define PSPLIT 32        // split-K for projection (8192 = 32*256)

// workspace layout (BYTE offsets)  -- total 29,483,008 B (< 30.9 MB known-good)
#define OFF_XN    0                                   // bf16 (N,D,SP)
#define OFF_SA    (OFF_XN + NB*DD*SP*2)               // bf16 (N,K,SP)
#define OFF_WPK   (OFF_SA + NB*KK*SP*2)               // bf16 Wpool frag-packed (32*8*64*8)
#define OFF_WCK   (OFF_WPK + 32*8*64*8*2)             // bf16 Wconv frag-packed (16*64*8)
#define OFF_VLADP (OFF_WCK + 16*64*8*2)               // f32 (N,NSPLIT,KD) packed C-layout
#define OFF_SASUM (OFF_VLADP + NB*NSPLIT*KD*4)        // f32 (N,NSPLIT,K)
#define OFF_VLADN (OFF_SASUM + NB*NSPLIT*KK*4)        // f32 (N,KD)
#define OFF_OUTP  (OFF_VLADN + NB*KD*4)               // f32 (PSPLIT,N,OUT)

typedef __attribute__((ext_vector_type(8))) short bf16x8;   // 8 bf16 = 4 VGPRs
typedef __attribute__((ext_vector_type(4))) float f32x4;

__device__ __forceinline__ unsigned int pk_bf16(float a, float b) {
    unsigned int ua = __builtin_bit_cast(unsigned int, a);
    unsigned int ub = __builtin_bit_cast(unsigned int, b);
    ua += 0x7FFFu + ((ua >> 16) & 1u);
    ub += 0x7FFFu + ((ub >> 16) & 1u);
    return (ua >> 16) | (ub & 0xFFFF0000u);
}
__device__ __forceinline__ unsigned short f2bf(float a) {
    unsigned int ua = __builtin_bit_cast(unsigned int, a);
    ua += 0x7FFFu + ((ua >> 16) & 1u);
    return (unsigned short)(ua >> 16);
}
__device__ __forceinline__ float bf2f(unsigned short u) {
    unsigned int v = ((unsigned int)u) << 16;
    return __builtin_bit_cast(float, v);
}

// ---------------------------------------------------------------------------
// K1: pack Wpool (128x1024) and Wconv (64x128) into MFMA A-fragment-ordered
// bf16 arrays so GEMM kernels load fragments straight from global (16B).
// Wpk layout: [kt(32)][mt(8)][lane(64)][8]   (A[d=mt*16+lm][c=kt*32+quad*8+j])
// Wck layout: [tile=kt*4+dsv (16)][lane(64)][8]  (A[k=kt*16+lm][d=dsv*32+quad*8+j])
// grid (9), block 256.
// ---------------------------------------------------------------------------
__global__ __launch_bounds__(256)
void pack_weights(const float* __restrict__ Wpool, const float* __restrict__ Wconv,
                  unsigned short* __restrict__ Wpk, unsigned short* __restrict__ Wck)
{
    const int b = blockIdx.x;
    const int t = threadIdx.x;
    if (b < 8) {
#pragma unroll
        for (int i = 0; i < 8; i++) {
            const int id = t + 256 * i;            // 0..2047
            const int ktl = id >> 9;               // 0..3
            const int mt  = (id >> 6) & 7;
            const int l   = id & 63;
            const int lm = l & 15, quad = l >> 4;
            const int kt = b * 4 + ktl;
            const int d = mt * 16 + lm;
            const int c = kt * 32 + quad * 8;
            const float4 v0 = *(const float4*)&Wpool[(size_t)d * CC + c];
            const float4 v1 = *(const float4*)&Wpool[(size_t)d * CC + c + 4];
            unsigned int* dst = (unsigned int*)&Wpk[(size_t)((kt * 8 + mt) * 64 + l) * 8];
            dst[0] = pk_bf16(v0.x, v0.y); dst[1] = pk_bf16(v0.z, v0.w);
            dst[2] = pk_bf16(v1.x, v1.y); dst[3] = pk_bf16(v1.z, v1.w);
        }
    } else {
#pragma unroll
        for (int i = 0; i < 4; i++) {
            const int id = t + 256 * i;            // 0..1023
            const int tile = id >> 6;
            const int l = id & 63;
            const int lm = l & 15, quad = l >> 4;
            const int k = (tile >> 2) * 16 + lm;
            const int d = (tile & 3) * 32 + quad * 8;
            const float4 v0 = *(const float4*)&Wconv[(size_t)k * DD + d];
            const float4 v1 = *(const float4*)&Wconv[(size_t)k * DD + d + 4];
            unsigned int* dst = (unsigned int*)&Wck[(size_t)(tile * 64 + l) * 8];
            dst[0] = pk_bf16(v0.x, v0.y); dst[1] = pk_bf16(v0.z, v0.w);
            dst[2] = pk_bf16(v1.x, v1.y); dst[3] = pk_bf16(v1.z, v1.w);
        }
    }
}

// ---------------------------------------------------------------------------
// K2: pool GEMM + bias + descriptor L2-norm + assign GEMM + softmax.
// Block tile 128d x 32s, grid (26, N) = 832 blocks.  ZERO barriers in the
// K-loop: A-frags are 16B global loads from Wpk; B-frags are built in
// registers from 8 strided x loads + pack.  3 barriers total (epilogue).
// ---------------------------------------------------------------------------
__global__ __launch_bounds__(256)
void pool_norm_assign(const float* __restrict__ x, const unsigned short* __restrict__ Wpk,
                      const float* __restrict__ bpool, const unsigned short* __restrict__ Wck,
                      const float* __restrict__ bconv,
                      unsigned short* __restrict__ xn, unsigned short* __restrict__ sa)
{
    const int n  = blockIdx.y;
    const int s0 = blockIdx.x * 32;
    const int t  = threadIdx.x;
    const int l  = t & 63;
    const int w  = t >> 6;
    const int wm = w & 1;        // d-half (64)
    const int wn = w >> 1;       // s-half (16)
    const int lm = l & 15;
    const int quad = l >> 4;

    __shared__ alignas(16) unsigned short xnT[32][136];  // [s][d] for assign B-frags
    __shared__ float red[2][32];
    __shared__ float sums[2][2][16];

    f32x4 acc[4];
#pragma unroll
    for (int i = 0; i < 4; i++) acc[i] = (f32x4){0.f, 0.f, 0.f, 0.f};

    const float* xb = x + (size_t)n * CC * SS;
    const int s = s0 + wn * 16 + lm;
    const int s_c = (s < SS) ? s : (SS - 1);     // clamp; pad lanes read garbage,
                                                 // neutralized downstream (sa guarded)
#pragma unroll 2
    for (int kt = 0; kt < 32; kt++) {
        // B fragment: x[c = kt*32+quad*8+j][s], 8 strided loads, pack in-register
        const float* bp = xb + (size_t)(kt * 32 + quad * 8) * SS + s_c;
        float rb[8];
#pragma unroll
        for (int j = 0; j < 8; j++) rb[j] = bp[(size_t)j * SS];
        union { unsigned int u[4]; bf16x8 v; } ub;
        ub.u[0] = pk_bf16(rb[0], rb[1]); ub.u[1] = pk_bf16(rb[2], rb[3]);
        ub.u[2] = pk_bf16(rb[4], rb[5]); ub.u[3] = pk_bf16(rb[6], rb[7]);
        const bf16x8 bfrag = ub.v;
#pragma unroll
        for (int i = 0; i < 4; i++) {
            const bf16x8 afrag = *(const bf16x8*)&Wpk[(size_t)((kt * 8 + wm * 4 + i) * 64 + l) * 8];
            acc[i] = __builtin_amdgcn_mfma_f32_16x16x32_bf16(afrag, bfrag, acc[i], 0, 0, 0);
        }
    }

    // ---- epilogue: bias + L2-norm over d (C layout: d=(wm*4+i)*16+quad*4+r, s=wn*16+lm)
    float ssq = 0.f;
#pragma unroll
    for (int i = 0; i < 4; i++) {
#pragma unroll
        for (int r = 0; r < 4; r++) {
            acc[i][r] += bpool[(wm * 4 + i) * 16 + quad * 4 + r];
            ssq += acc[i][r] * acc[i][r];
        }
    }
    ssq += __shfl_xor(ssq, 16, 64);
    ssq += __shfl_xor(ssq, 32, 64);
    if (quad == 0) red[wm][wn * 16 + lm] = ssq;
    __syncthreads();
    const int sl = wn * 16 + lm;
    const float scale = 1.f / fmaxf(sqrtf(red[0][sl] + red[1][sl]), 1e-12f);
    unsigned short* xnp = xn + (size_t)n * DD * SP;
#pragma unroll
    for (int i = 0; i < 4; i++) {
        const float v0 = acc[i][0] * scale, v1 = acc[i][1] * scale;
        const float v2 = acc[i][2] * scale, v3 = acc[i][3] * scale;
        const int dbase = (wm * 4 + i) * 16 + quad * 4;
        unsigned int* pT = (unsigned int*)&xnT[sl][dbase];
        pT[0] = pk_bf16(v0, v1);
        pT[1] = pk_bf16(v2, v3);
        xnp[(size_t)(dbase + 0) * SP + s] = f2bf(v0);   // pad s: garbage values, but
        xnp[(size_t)(dbase + 1) * SP + s] = f2bf(v1);   // vlad multiplies them by sa==0
        xnp[(size_t)(dbase + 2) * SP + s] = f2bf(v2);
        xnp[(size_t)(dbase + 3) * SP + s] = f2bf(v3);
    }
    __syncthreads();

    // ---- assign GEMM: logits[64k x 32s] = Wconv @ xnT, K=128 in 4 dsv steps
    const int kth = w & 1;     // k-half
    const int ntA = w >> 1;    // s-half
    f32x4 acc2[2];
    acc2[0] = (f32x4){0.f, 0.f, 0.f, 0.f};
    acc2[1] = (f32x4){0.f, 0.f, 0.f, 0.f};
#pragma unroll
    for (int dsv = 0; dsv < 4; dsv++) {
        const bf16x8 bfrag = *(const bf16x8*)&xnT[ntA * 16 + lm][dsv * 32 + quad * 8];
#pragma unroll
        for (int j = 0; j < 2; j++) {
            const int tile = ((kth * 2 + j) * 4 + dsv);
            const bf16x8 afrag = *(const bf16x8*)&Wck[(size_t)(tile * 64 + l) * 8];
            acc2[j] = __builtin_amdgcn_mfma_f32_16x16x32_bf16(afrag, bfrag, acc2[j], 0, 0, 0);
        }
    }
    // softmax over k (|logits| <= ~1.3 since x-hat is unit norm: no max-sub needed)
    float ex[2][4]; float psum = 0.f;
#pragma unroll
    for (int j = 0; j < 2; j++)
#pragma unroll
        for (int r = 0; r < 4; r++) {
            const int k = (kth * 2 + j) * 16 + quad * 4 + r;
            const float e = expf(acc2[j][r] + bconv[k]);
            ex[j][r] = e; psum += e;
        }
    psum += __shfl_xor(psum, 16, 64);
    psum += __shfl_xor(psum, 32, 64);
    if (quad == 0) sums[kth][ntA][lm] = psum;
    __syncthreads();
    const float inv = 1.f / (sums[0][ntA][lm] + sums[1][ntA][lm]);
    const int s2 = s0 + ntA * 16 + lm;
    const bool val2 = s2 < SS;
    unsigned short* sap = sa + (size_t)n * KK * SP;
#pragma unroll
    for (int j = 0; j < 2; j++)
#pragma unroll
        for (int r = 0; r < 4; r++) {
            const int k = (kth * 2 + j) * 16 + quad * 4 + r;
            sap[(size_t)k * SP + s2] = val2 ? f2bf(ex[j][r] * inv) : (unsigned short)0;
        }
}

// ---------------------------------------------------------------------------
// K3: vlad GEMM (MFMA, fragment loads direct from global, no LDS, no barrier):
// partials over s-ranges of 64.  C stored PACKED: vp[(kq*DD+d)*4 + r] where
// k = kq*4+r  -> 16B f32x4 stores.
// grid (NSPLIT, N) = 416 blocks; wave tile 32k x 64d.
// ---------------------------------------------------------------------------
__global__ __launch_bounds__(256)
void vlad_mfma(const unsigned short* __restrict__ xn, const unsigned short* __restrict__ sa,
               float* __restrict__ vladp, float* __restrict__ sasump)
{
    const int p = blockIdx.x;
    const int n = blockIdx.y;
    const int t = threadIdx.x;
    const int l = t & 63;
    const int w = t >> 6;
    const int kth = w & 1, nh = w >> 1;
    const int lm = l & 15, quad = l >> 4;

    const unsigned short* sap = sa + (size_t)n * KK * SP;
    const unsigned short* xnp = xn + (size_t)n * DD * SP;

    f32x4 acc[2][4];
#pragma unroll
    for (int j = 0; j < 2; j++)
#pragma unroll
        for (int i = 0; i < 4; i++) acc[j][i] = (f32x4){0.f, 0.f, 0.f, 0.f};

#pragma unroll
    for (int st = 0; st < 2; st++) {
        const int sb = p * 64 + st * 32 + quad * 8;
        bf16x8 af[2], bfv[4];
#pragma unroll
        for (int j = 0; j < 2; j++)
            af[j] = *(const bf16x8*)&sap[(size_t)((kth * 2 + j) * 16 + lm) * SP + sb];
#pragma unroll
        for (int i = 0; i < 4; i++)
            bfv[i] = *(const bf16x8*)&xnp[(size_t)((nh * 4 + i) * 16 + lm) * SP + sb];
#pragma unroll
        for (int j = 0; j < 2; j++)
#pragma unroll
            for (int i = 0; i < 4; i++)
                acc[j][i] = __builtin_amdgcn_mfma_f32_16x16x32_bf16(af[j], bfv[i], acc[j][i], 0, 0, 0);
    }

    float* vp = vladp + ((size_t)n * NSPLIT + p) * KD;
#pragma unroll
    for (int j = 0; j < 2; j++)
#pragma unroll
        for (int i = 0; i < 4; i++) {
            const int kq = (kth * 2 + j) * 4 + quad;          // k = kq*4 + r
            const int d  = (nh * 4 + i) * 16 + lm;
            *(f32x4*)&vp[(size_t)(kq * DD + d) * 4] = acc[j][i];
        }

    if (t < KK) {
        float sm = 0.f;
        const unsigned short* rp = &sap[(size_t)t * SP + p * 64];
#pragma unroll
        for (int c = 0; c < 64; c++) sm += bf2f(rp[c]);
        sasump[((size_t)n * NSPLIT + p) * KK + t] = sm;
    }
}

// ---------------------------------------------------------------------------
// K4: reduce NSPLIT partials, subtract centroids*sasum, L2-norm over k,
// write vladn (N, KD) fp32.  grid (16 d-groups, N) = 512 blocks.
// thread: d = dg*8 + (t>>5);  k = 2*(t&31) (+1).  Reads packed vladp.
// ---------------------------------------------------------------------------
__global__ __launch_bounds__(256)
void vlad_finish(const float* __restrict__ vladp, const float* __restrict__ sasump,
                 const float* __restrict__ centroids, float* __restrict__ vladn)
{
    const int dg = blockIdx.x;
    const int n  = blockIdx.y;
    const int t  = threadIdx.x;
    const int d  = dg * 8 + (t >> 5);
    const int k0 = (t & 31) * 2;

    __shared__ float sas[KK];
    if (t < KK) {
        float sm = 0.f;
#pragma unroll
        for (int p = 0; p < NSPLIT; p++) sm += sasump[((size_t)n * NSPLIT + p) * KK + t];
        sas[t] = sm;
    }
    __syncthreads();

    const int kq = k0 >> 2, r0 = k0 & 3;         // r0 in {0,2}; k0,k0+1 share kq
    float v0 = 0.f, v1 = 0.f;
#pragma unroll
    for (int p = 0; p < NSPLIT; p++) {
        const float2 pr = *(const float2*)&vladp[((size_t)n * NSPLIT + p) * KD + (size_t)(kq * DD + d) * 4 + r0];
        v0 += pr.x; v1 += pr.y;
    }
    v0 -= centroids[(size_t)k0 * DD + d] * sas[k0];
    v1 -= centroids[(size_t)(k0 + 1) * DD + d] * sas[k0 + 1];

    float ssq = v0 * v0 + v1 * v1;
    ssq += __shfl_xor(ssq, 1, 64);
    ssq += __shfl_xor(ssq, 2, 64);
    ssq += __shfl_xor(ssq, 4, 64);
    ssq += __shfl_xor(ssq, 8, 64);
    ssq += __shfl_xor(ssq, 16, 64);              // full 32-lane k-group for this d
    const float scale = 1.f / fmaxf(sqrtf(ssq), 1e-12f);

    float* vo = vladn + (size_t)n * KD;
    vo[(size_t)k0 * DD + d]       = v0 * scale;
    vo[(size_t)(k0 + 1) * DD + d] = v1 * scale;
}

// ---------------------------------------------------------------------------
// K5: projection partials: outp[p,n,o] = vladn[n, c-slice] . Wproj[o, c-slice]
// grid (OUT/64=16, PSPLIT=32) = 512 blocks; float4 loads + register prefetch.
// ---------------------------------------------------------------------------
__global__ __launch_bounds__(256)
void proj_partial_kernel(const float* __restrict__ vladn, const float* __restrict__ Wproj,
                         float* __restrict__ outp)
{
    const int o0 = blockIdx.x * 64;
    const int c0 = blockIdx.y * (KD / PSPLIT);   // 256-wide K slice
    const int t  = threadIdx.x;
    const int ow = t & 31, nw = t >> 5;
    const int wr = t & 63, wq = t >> 6;
    const int vr = t & 31, vq = t >> 5;

    __shared__ float Ws[64][33];
    __shared__ float Vs[32][33];

    float acc[2][4];
#pragma unroll
    for (int i = 0; i < 2; i++)
#pragma unroll
        for (int j = 0; j < 4; j++) acc[i][j] = 0.f;

    float4 w0 = *(const float4*)&Wproj[(size_t)(o0 + wr) * KD + c0 + wq * 8];
    float4 w1 = *(const float4*)&Wproj[(size_t)(o0 + wr) * KD + c0 + wq * 8 + 4];
    float4 v4 = *(const float4*)&vladn[(size_t)vr * KD + c0 + vq * 4];

    for (int cc0 = c0; cc0 < c0 + KD / PSPLIT; cc0 += 32) {
        Ws[wr][wq * 8 + 0] = w0.x; Ws[wr][wq * 8 + 1] = w0.y;
        Ws[wr][wq * 8 + 2] = w0.z; Ws[wr][wq * 8 + 3] = w0.w;
        Ws[wr][wq * 8 + 4] = w1.x; Ws[wr][wq * 8 + 5] = w1.y;
        Ws[wr][wq * 8 + 6] = w1.z; Ws[wr][wq * 8 + 7] = w1.w;
        Vs[vr][vq * 4 + 0] = v4.x; Vs[vr][vq * 4 + 1] = v4.y;
        Vs[vr][vq * 4 + 2] = v4.z; Vs[vr][vq * 4 + 3] = v4.w;
        __syncthreads();
        if (cc0 + 32 < c0 + KD / PSPLIT) {
            w0 = *(const float4*)&Wproj[(size_t)(o0 + wr) * KD + cc0 + 32 + wq * 8];
            w1 = *(const float4*)&Wproj[(size_t)(o0 + wr) * KD + cc0 + 32 + wq * 8 + 4];
            v4 = *(const float4*)&vladn[(size_t)vr * KD + cc0 + 32 + vq * 4];
        }
#pragma unroll
        for (int cc = 0; cc < 32; cc++) {
            float wv[2], vv[4];
            wv[0] = Ws[ow][cc]; wv[1] = Ws[ow + 32][cc];
#pragma unroll
            for (int j = 0; j < 4; j++) vv[j] = Vs[nw + 8 * j][cc];
#pragma unroll
            for (int i = 0; i < 2; i++)
#pragma unroll
                for (int j = 0; j < 4; j++) acc[i][j] += wv[i] * vv[j];
        }
        __syncthreads();
    }

#pragma unroll
    for (int i = 0; i < 2; i++)
#pragma unroll
        for (int j = 0; j < 4; j++) {
            const int o = o0 + ow + 32 * i;
            const int nn = nw + 8 * j;
            outp[((size_t)blockIdx.y * NB + nn) * OUTD + o] = acc[i][j];
        }
}

// ---------------------------------------------------------------------------
// K6: sum projection partials + bproj, final L2 norm over OUT, write d_out.
// grid (N), block 256; thread owns o = 4t..4t+3 as float4.
// ---------------------------------------------------------------------------
__global__ __launch_bounds__(256)
void final_norm_kernel(const float* __restrict__ outp, const float* __restrict__ bproj,
                       float* __restrict__ out)
{
    const int n = blockIdx.x;
    const int t = threadIdx.x;
    const int o4 = t * 4;

    float4 a = *(const float4*)&bproj[o4];
#pragma unroll
    for (int p = 0; p < PSPLIT; p++) {
        const float4 pr = *(const float4*)&outp[((size_t)p * NB + n) * OUTD + o4];
        a.x += pr.x; a.y += pr.y; a.z += pr.z; a.w += pr.w;
    }
    float ssp = a.x * a.x + a.y * a.y + a.z * a.z + a.w * a.w;
#pragma unroll
    for (int off = 32; off > 0; off >>= 1) ssp += __shfl_down(ssp, off, 64);
    __shared__ float rs[4];
    if ((t & 63) == 0) rs[t >> 6] = ssp;
    __syncthreads();
    const float total = rs[0] + rs[1] + rs[2] + rs[3];
    const float scale = 1.f / fmaxf(sqrtf(total), 1e-12f);
    float4 o;
    o.x = a.x * scale; o.y = a.y * scale; o.z = a.z * scale; o.w = a.w * scale;
    *(float4*)&out[(size_t)n * OUTD + o4] = o;
}

// ---------------------------------------------------------------------------
extern "C" void kernel_launch(void* const* d_in, const int* in_sizes, int n_in,
                              void* d_out, int out_size, void* d_ws, size_t ws_size,
                              hipStream_t stream)
{
    const float* x         = (const float*)d_in[0];
    const float* Wpool     = (const float*)d_in[1];
    const float* bpool     = (const float*)d_in[2];
    const float* Wconv     = (const float*)d_in[3];
    const float* bconv     = (const float*)d_in[4];
    const float* centroids = (const float*)d_in[5];
    const float* Wproj     = (const float*)d_in[6];
    const float* bproj     = (const float*)d_in[7];
    float* out = (float*)d_out;
    char*  wsb = (char*)d_ws;

    unsigned short* xn     = (unsigned short*)(wsb + OFF_XN);
    unsigned short* sa     = (unsigned short*)(wsb + OFF_SA);
    unsigned short* Wpk    = (unsigned short*)(wsb + OFF_WPK);
    unsigned short* Wck    = (unsigned short*)(wsb + OFF_WCK);
    float*          vladp  = (float*)(wsb + OFF_VLADP);
    float*          sasump = (float*)(wsb + OFF_SASUM);
    float*          vladn  = (float*)(wsb + OFF_VLADN);
    float*          outp   = (float*)(wsb + OFF_OUTP);

    pack_weights<<<dim3(9), 256, 0, stream>>>(Wpool, Wconv, Wpk, Wck);
    pool_norm_assign<<<dim3(SP / 32, NB), 256, 0, stream>>>(x, Wpk, bpool, Wck, bconv, xn, sa);
    vlad_mfma<<<dim3(NSPLIT, NB), 256, 0, stream>>>(xn, sa, vladp, sasump);
    vlad_finish<<<dim3(16, NB), 256, 0, stream>>>(vladp, sasump, centroids, vladn);
    proj_partial_kernel<<<dim3(OUTD / 64, PSPLIT), 256, 0, stream>>>(vladn, Wproj, outp);
    final_norm_kernel<<<dim3(NB), 256, 0, stream>>>(outp, bproj, out);
}

// Round 5
// 234.279 us; speedup vs baseline: 2.2433x; 1.0798x over previous
//
#include <hip/hip_runtime.h>
#include <math.h>

#define NB 32
#define CC 1024
#define SS 784
#define SP 832           // padded S (52*16); sa pad region is zeroed
#define DD 128
#define KK 64
#define OUTD 1024
#define KD 8192          // K*D
#define NSPLIT 13        // vlad s-splits (64 s each)
#define PSPLIT 32        // split-K for projection (8192 = 32*256)

// workspace layout (BYTE offsets)  -- total ~29.5 MB (< 30.9 MB known-good)
#define OFF_XN    0                                   // bf16 (N,D,SP)
#define OFF_SA    (OFF_XN + NB*DD*SP*2)               // bf16 (N,K,SP)
#define OFF_WPK   (OFF_SA + NB*KK*SP*2)               // bf16 Wpool frag-packed (32*8*64*8)
#define OFF_WCK   (OFF_WPK + 32*8*64*8*2)             // bf16 Wconv frag-packed (16*64*8)
#define OFF_VLADP (OFF_WCK + 16*64*8*2)               // f32 (N,NSPLIT,KD) packed C-layout
#define OFF_SASUM (OFF_VLADP + NB*NSPLIT*KD*4)        // f32 (N,NSPLIT,K)
#define OFF_VLADN (OFF_SASUM + NB*NSPLIT*KK*4)        // f32 (N,KD)
#define OFF_OUTP  (OFF_VLADN + NB*KD*4)               // f32 (PSPLIT,N,OUT)

typedef __attribute__((ext_vector_type(8))) short bf16x8;   // 8 bf16 = 4 VGPRs
typedef __attribute__((ext_vector_type(4))) float f32x4;

__device__ __forceinline__ unsigned int pk_bf16(float a, float b) {
    unsigned int ua = __builtin_bit_cast(unsigned int, a);
    unsigned int ub = __builtin_bit_cast(unsigned int, b);
    ua += 0x7FFFu + ((ua >> 16) & 1u);
    ub += 0x7FFFu + ((ub >> 16) & 1u);
    return (ua >> 16) | (ub & 0xFFFF0000u);
}
__device__ __forceinline__ unsigned short f2bf(float a) {
    unsigned int ua = __builtin_bit_cast(unsigned int, a);
    ua += 0x7FFFu + ((ua >> 16) & 1u);
    return (unsigned short)(ua >> 16);
}
__device__ __forceinline__ float bf2f(unsigned short u) {
    unsigned int v = ((unsigned int)u) << 16;
    return __builtin_bit_cast(float, v);
}

// ---------------------------------------------------------------------------
// K1: pack Wpool (128x1024) and Wconv (64x128) into MFMA A-fragment-ordered
// bf16 arrays.  Wpk: [kt(32)][mt(8)][lane(64)][8]; Wck: [tile(16)][lane(64)][8]
// ---------------------------------------------------------------------------
__global__ __launch_bounds__(256)
void pack_weights(const float* __restrict__ Wpool, const float* __restrict__ Wconv,
                  unsigned short* __restrict__ Wpk, unsigned short* __restrict__ Wck)
{
    const int b = blockIdx.x;
    const int t = threadIdx.x;
    if (b < 8) {
#pragma unroll
        for (int i = 0; i < 8; i++) {
            const int id = t + 256 * i;            // 0..2047
            const int ktl = id >> 9;               // 0..3
            const int mt  = (id >> 6) & 7;
            const int l   = id & 63;
            const int lm = l & 15, quad = l >> 4;
            const int kt = b * 4 + ktl;
            const int d = mt * 16 + lm;
            const int c = kt * 32 + quad * 8;
            const float4 v0 = *(const float4*)&Wpool[(size_t)d * CC + c];
            const float4 v1 = *(const float4*)&Wpool[(size_t)d * CC + c + 4];
            unsigned int* dst = (unsigned int*)&Wpk[(size_t)((kt * 8 + mt) * 64 + l) * 8];
            dst[0] = pk_bf16(v0.x, v0.y); dst[1] = pk_bf16(v0.z, v0.w);
            dst[2] = pk_bf16(v1.x, v1.y); dst[3] = pk_bf16(v1.z, v1.w);
        }
    } else {
#pragma unroll
        for (int i = 0; i < 4; i++) {
            const int id = t + 256 * i;            // 0..1023
            const int tile = id >> 6;
            const int l = id & 63;
            const int lm = l & 15, quad = l >> 4;
            const int k = (tile >> 2) * 16 + lm;
            const int d = (tile & 3) * 32 + quad * 8;
            const float4 v0 = *(const float4*)&Wconv[(size_t)k * DD + d];
            const float4 v1 = *(const float4*)&Wconv[(size_t)k * DD + d + 4];
            unsigned int* dst = (unsigned int*)&Wck[(size_t)(tile * 64 + l) * 8];
            dst[0] = pk_bf16(v0.x, v0.y); dst[1] = pk_bf16(v0.z, v0.w);
            dst[2] = pk_bf16(v1.x, v1.y); dst[3] = pk_bf16(v1.z, v1.w);
        }
    }
}

// ---------------------------------------------------------------------------
// K2: pool GEMM + bias + L2-norm + assign GEMM + softmax.
// Block tile 128d x 16s, grid (52, N) = 1664 blocks, LDS ~37 KB -> 4 blocks/CU.
// PHASE 1: burst-stage x[all 1024 c][16 s] -> LDS bf16 [cblk(128)][s(16)][8]
//   (64 fully-independent global loads per thread; NOTHING depends on them
//    until one barrier -> streams at HBM queue depth).
// PHASE 2: K-loop (32 steps): B-frag = contiguous ds_read_b128 (conflict-free),
//   A-frags = 16B global loads from L2-resident Wpk (prefetched). No barriers.
// PHASE 3: bias + norm + assign MFMA (Wck) + softmax.  xn/sa written in
//   vlad-fragment layouts.
// ---------------------------------------------------------------------------
__global__ __launch_bounds__(256)
void pool_norm_assign(const float* __restrict__ x, const unsigned short* __restrict__ Wpk,
                      const float* __restrict__ bpool, const unsigned short* __restrict__ Wck,
                      const float* __restrict__ bconv,
                      unsigned short* __restrict__ xn, unsigned short* __restrict__ sa)
{
    const int n  = blockIdx.y;
    const int s0 = blockIdx.x * 16;
    const int t  = threadIdx.x;
    const int l  = t & 63;
    const int w  = t >> 6;       // wave 0..3 -> mt pair {2w, 2w+1}
    const int lm = l & 15;
    const int quad = l >> 4;

    __shared__ alignas(16) unsigned short Bst[128 * 16 * 8];  // 32 KB
    __shared__ alignas(16) unsigned short xnT[16 * 16 * 8];   // 4 KB [dblk][s][8]
    __shared__ float red[4][16];
    __shared__ float sums[4][16];

    // ---- PHASE 1: stage x slice
    {
        const int s_l = t & 15;
        const int cb0 = t >> 4;                  // 0..15
        const int sg  = s0 + s_l;
        const int s_c = (sg < SS) ? sg : (SS - 1);
        const float* xb = x + (size_t)n * CC * SS + s_c;
#pragma unroll
        for (int it = 0; it < 8; it++) {
            const int cblk = cb0 + 16 * it;
            const float* xp = xb + (size_t)(cblk * 8) * SS;
            float v[8];
#pragma unroll
            for (int j = 0; j < 8; j++) v[j] = xp[(size_t)j * SS];
            unsigned int* dst = (unsigned int*)&Bst[(size_t)(cblk * 16 + s_l) * 8];
            dst[0] = pk_bf16(v[0], v[1]); dst[1] = pk_bf16(v[2], v[3]);
            dst[2] = pk_bf16(v[4], v[5]); dst[3] = pk_bf16(v[6], v[7]);
        }
    }
    __syncthreads();

    // ---- PHASE 2: pool GEMM K-loop (no barriers, A prefetched)
    f32x4 acc[2];
    acc[0] = (f32x4){0.f, 0.f, 0.f, 0.f};
    acc[1] = (f32x4){0.f, 0.f, 0.f, 0.f};

    bf16x8 a_nxt[2];
#pragma unroll
    for (int i = 0; i < 2; i++)
        a_nxt[i] = *(const bf16x8*)&Wpk[(size_t)((0 * 8 + w * 2 + i) * 64 + l) * 8];

    for (int kt = 0; kt < 32; kt++) {
        const bf16x8 a0 = a_nxt[0], a1 = a_nxt[1];
        if (kt < 31) {
#pragma unroll
            for (int i = 0; i < 2; i++)
                a_nxt[i] = *(const bf16x8*)&Wpk[(size_t)(((kt + 1) * 8 + w * 2 + i) * 64 + l) * 8];
        }
        const bf16x8 bfrag = *(const bf16x8*)&Bst[(size_t)((kt * 4 + quad) * 16 + lm) * 8];
        acc[0] = __builtin_amdgcn_mfma_f32_16x16x32_bf16(a0, bfrag, acc[0], 0, 0, 0);
        acc[1] = __builtin_amdgcn_mfma_f32_16x16x32_bf16(a1, bfrag, acc[1], 0, 0, 0);
    }

    // ---- PHASE 3a: bias + L2-norm over d.  C layout: d=(2w+i)*16+quad*4+r, s=lm
    float vals[2][4];
    float ssq = 0.f;
#pragma unroll
    for (int i = 0; i < 2; i++)
#pragma unroll
        for (int r = 0; r < 4; r++) {
            const int d = (w * 2 + i) * 16 + quad * 4 + r;
            const float v = acc[i][r] + bpool[d];
            vals[i][r] = v; ssq += v * v;
        }
    ssq += __shfl_xor(ssq, 16, 64);
    ssq += __shfl_xor(ssq, 32, 64);
    if (quad == 0) red[w][lm] = ssq;
    __syncthreads();
    const float scale = 1.f / fmaxf(sqrtf(red[0][lm] + red[1][lm] + red[2][lm] + red[3][lm]), 1e-12f);
    const int sg = s0 + lm;
    unsigned short* xnp = xn + (size_t)n * DD * SP;
#pragma unroll
    for (int i = 0; i < 2; i++)
#pragma unroll
        for (int r = 0; r < 4; r++) {
            const int d = (w * 2 + i) * 16 + quad * 4 + r;
            const float v = vals[i][r] * scale;
            xnp[(size_t)d * SP + sg] = f2bf(v);   // pad s: garbage, neutralized by sa==0
            xnT[(size_t)(((d >> 3) * 16) + lm) * 8 + (d & 7)] = f2bf(v);
        }
    __syncthreads();

    // ---- PHASE 3b: assign GEMM (64k x 16s), wave w -> k-tile w
    f32x4 acc2 = (f32x4){0.f, 0.f, 0.f, 0.f};
#pragma unroll
    for (int dsv = 0; dsv < 4; dsv++) {
        const bf16x8 bfrag = *(const bf16x8*)&xnT[(size_t)((dsv * 4 + quad) * 16 + lm) * 8];
        const bf16x8 afrag = *(const bf16x8*)&Wck[(size_t)((w * 4 + dsv) * 64 + l) * 8];
        acc2 = __builtin_amdgcn_mfma_f32_16x16x32_bf16(afrag, bfrag, acc2, 0, 0, 0);
    }
    // softmax over k (|logits| <= ~1.5 since x-hat unit-norm: no max-sub needed)
    float e[4]; float ps = 0.f;
#pragma unroll
    for (int r = 0; r < 4; r++) {
        const int k = w * 16 + quad * 4 + r;
        e[r] = expf(acc2[r] + bconv[k]);
        ps += e[r];
    }
    ps += __shfl_xor(ps, 16, 64);
    ps += __shfl_xor(ps, 32, 64);
    if (quad == 0) sums[w][lm] = ps;
    __syncthreads();
    const float inv = 1.f / (sums[0][lm] + sums[1][lm] + sums[2][lm] + sums[3][lm]);
    const bool val2 = sg < SS;
    unsigned short* sap = sa + (size_t)n * KK * SP;
#pragma unroll
    for (int r = 0; r < 4; r++) {
        const int k = w * 16 + quad * 4 + r;
        sap[(size_t)k * SP + sg] = val2 ? f2bf(e[r] * inv) : (unsigned short)0;
    }
}

// ---------------------------------------------------------------------------
// K3: vlad GEMM (MFMA, fragment loads direct from global, no LDS, no barrier):
// C stored PACKED: vp[(kq*DD+d)*4 + r], k = kq*4+r -> 16B f32x4 stores.
// grid (NSPLIT, N) = 416 blocks; wave tile 32k x 64d.
// ---------------------------------------------------------------------------
__global__ __launch_bounds__(256)
void vlad_mfma(const unsigned short* __restrict__ xn, const unsigned short* __restrict__ sa,
               float* __restrict__ vladp, float* __restrict__ sasump)
{
    const int p = blockIdx.x;
    const int n = blockIdx.y;
    const int t = threadIdx.x;
    const int l = t & 63;
    const int w = t >> 6;
    const int kth = w & 1, nh = w >> 1;
    const int lm = l & 15, quad = l >> 4;

    const unsigned short* sap = sa + (size_t)n * KK * SP;
    const unsigned short* xnp = xn + (size_t)n * DD * SP;

    f32x4 acc[2][4];
#pragma unroll
    for (int j = 0; j < 2; j++)
#pragma unroll
        for (int i = 0; i < 4; i++) acc[j][i] = (f32x4){0.f, 0.f, 0.f, 0.f};

#pragma unroll
    for (int st = 0; st < 2; st++) {
        const int sb = p * 64 + st * 32 + quad * 8;
        bf16x8 af[2], bfv[4];
#pragma unroll
        for (int j = 0; j < 2; j++)
            af[j] = *(const bf16x8*)&sap[(size_t)((kth * 2 + j) * 16 + lm) * SP + sb];
#pragma unroll
        for (int i = 0; i < 4; i++)
            bfv[i] = *(const bf16x8*)&xnp[(size_t)((nh * 4 + i) * 16 + lm) * SP + sb];
#pragma unroll
        for (int j = 0; j < 2; j++)
#pragma unroll
            for (int i = 0; i < 4; i++)
                acc[j][i] = __builtin_amdgcn_mfma_f32_16x16x32_bf16(af[j], bfv[i], acc[j][i], 0, 0, 0);
    }

    float* vp = vladp + ((size_t)n * NSPLIT + p) * KD;
#pragma unroll
    for (int j = 0; j < 2; j++)
#pragma unroll
        for (int i = 0; i < 4; i++) {
            const int kq = (kth * 2 + j) * 4 + quad;          // k = kq*4 + r
            const int d  = (nh * 4 + i) * 16 + lm;
            *(f32x4*)&vp[(size_t)(kq * DD + d) * 4] = acc[j][i];
        }

    if (t < KK) {
        float sm = 0.f;
        const unsigned short* rp = &sap[(size_t)t * SP + p * 64];
#pragma unroll
        for (int c = 0; c < 64; c++) sm += bf2f(rp[c]);
        sasump[((size_t)n * NSPLIT + p) * KK + t] = sm;
    }
}

// ---------------------------------------------------------------------------
// K4: reduce NSPLIT partials (f32x4 vector reads), subtract centroids*sasum,
// L2-norm over k, write vladn.  grid (DD/16=8, N) = 256 blocks.
// thread: kq = t&15 (k=kq*4+r), d = dg*16 + (t>>4).
// ---------------------------------------------------------------------------
__global__ __launch_bounds__(256)
void vlad_finish(const float* __restrict__ vladp, const float* __restrict__ sasump,
                 const float* __restrict__ centroids, float* __restrict__ vladn)
{
    const int dg = blockIdx.x;
    const int n  = blockIdx.y;
    const int t  = threadIdx.x;
    const int kq = t & 15;
    const int d  = dg * 16 + (t >> 4);

    __shared__ float sas[KK];
    if (t < KK) {
        float sm = 0.f;
#pragma unroll
        for (int p = 0; p < NSPLIT; p++) sm += sasump[((size_t)n * NSPLIT + p) * KK + t];
        sas[t] = sm;
    }
    __syncthreads();

    f32x4 v = (f32x4){0.f, 0.f, 0.f, 0.f};
#pragma unroll
    for (int p = 0; p < NSPLIT; p++) {
        const f32x4 pr = *(const f32x4*)&vladp[((size_t)n * NSPLIT + p) * KD + (size_t)(kq * DD + d) * 4];
        v += pr;
    }
#pragma unroll
    for (int r = 0; r < 4; r++)
        v[r] -= centroids[(size_t)(kq * 4 + r) * DD + d] * sas[kq * 4 + r];

    float ssq = v[0] * v[0] + v[1] * v[1] + v[2] * v[2] + v[3] * v[3];
    ssq += __shfl_xor(ssq, 1, 64);
    ssq += __shfl_xor(ssq, 2, 64);
    ssq += __shfl_xor(ssq, 4, 64);
    ssq += __shfl_xor(ssq, 8, 64);               // full 16-kq group for this d
    const float scale = 1.f / fmaxf(sqrtf(ssq), 1e-12f);

    float* vo = vladn + (size_t)n * KD;
#pragma unroll
    for (int r = 0; r < 4; r++)
        vo[(size_t)(kq * 4 + r) * DD + d] = v[r] * scale;
}

// ---------------------------------------------------------------------------
// K5: projection via MFMA, barrier-free, no LDS.
// out[n][o] = vladn[n][c] . Wproj[o][c]; A=vladn (m=n), B=Wproj (ndim=o), k=c.
// grid (OUT/64=16, PSPLIT=32) = 512 blocks; 8 K-steps of 32 c; operands packed
// to bf16 in-register from independent float4 loads.
// ---------------------------------------------------------------------------
__global__ __launch_bounds__(256)
void proj_mfma(const float* __restrict__ vladn, const float* __restrict__ Wproj,
               float* __restrict__ outp)
{
    const int o0 = blockIdx.x * 64;
    const int c0 = blockIdx.y * (KD / PSPLIT);   // 256-wide c slice
    const int t  = threadIdx.x;
    const int l  = t & 63;
    const int w  = t >> 6;
    const int lm = l & 15, quad = l >> 4;
    const int o  = o0 + w * 16 + lm;

    f32x4 acc[2];
    acc[0] = (f32x4){0.f, 0.f, 0.f, 0.f};
    acc[1] = (f32x4){0.f, 0.f, 0.f, 0.f};

#pragma unroll 2
    for (int kt = 0; kt < 8; kt++) {
        const int c = c0 + kt * 32 + quad * 8;
        const float4 b0 = *(const float4*)&Wproj[(size_t)o * KD + c];
        const float4 b1 = *(const float4*)&Wproj[(size_t)o * KD + c + 4];
        float4 a00 = *(const float4*)&vladn[(size_t)(0 * 16 + lm) * KD + c];
        float4 a01 = *(const float4*)&vladn[(size_t)(0 * 16 + lm) * KD + c + 4];
        float4 a10 = *(const float4*)&vladn[(size_t)(16 + lm) * KD + c];
        float4 a11 = *(const float4*)&vladn[(size_t)(16 + lm) * KD + c + 4];
        union { unsigned int u[4]; bf16x8 v; } ub, ua0, ua1;
        ub.u[0] = pk_bf16(b0.x, b0.y); ub.u[1] = pk_bf16(b0.z, b0.w);
        ub.u[2] = pk_bf16(b1.x, b1.y); ub.u[3] = pk_bf16(b1.z, b1.w);
        ua0.u[0] = pk_bf16(a00.x, a00.y); ua0.u[1] = pk_bf16(a00.z, a00.w);
        ua0.u[2] = pk_bf16(a01.x, a01.y); ua0.u[3] = pk_bf16(a01.z, a01.w);
        ua1.u[0] = pk_bf16(a10.x, a10.y); ua1.u[1] = pk_bf16(a10.z, a10.w);
        ua1.u[2] = pk_bf16(a11.x, a11.y); ua1.u[3] = pk_bf16(a11.z, a11.w);
        acc[0] = __builtin_amdgcn_mfma_f32_16x16x32_bf16(ua0.v, ub.v, acc[0], 0, 0, 0);
        acc[1] = __builtin_amdgcn_mfma_f32_16x16x32_bf16(ua1.v, ub.v, acc[1], 0, 0, 0);
    }

    // C layout: col lm -> o (matches B), row quad*4+r -> n = a*16+quad*4+r
#pragma unroll
    for (int a = 0; a < 2; a++)
#pragma unroll
        for (int r = 0; r < 4; r++) {
            const int nn = a * 16 + quad * 4 + r;
            outp[((size_t)blockIdx.y * NB + nn) * OUTD + o] = acc[a][r];
        }
}

// ---------------------------------------------------------------------------
// K6: sum projection partials + bproj, final L2 norm over OUT, write d_out.
// ---------------------------------------------------------------------------
__global__ __launch_bounds__(256)
void final_norm_kernel(const float* __restrict__ outp, const float* __restrict__ bproj,
                       float* __restrict__ out)
{
    const int n = blockIdx.x;
    const int t = threadIdx.x;
    const int o4 = t * 4;

    float4 a = *(const float4*)&bproj[o4];
#pragma unroll
    for (int p = 0; p < PSPLIT; p++) {
        const float4 pr = *(const float4*)&outp[((size_t)p * NB + n) * OUTD + o4];
        a.x += pr.x; a.y += pr.y; a.z += pr.z; a.w += pr.w;
    }
    float ssp = a.x * a.x + a.y * a.y + a.z * a.z + a.w * a.w;
#pragma unroll
    for (int off = 32; off > 0; off >>= 1) ssp += __shfl_down(ssp, off, 64);
    __shared__ float rs[4];
    if ((t & 63) == 0) rs[t >> 6] = ssp;
    __syncthreads();
    const float total = rs[0] + rs[1] + rs[2] + rs[3];
    const float scale = 1.f / fmaxf(sqrtf(total), 1e-12f);
    float4 o;
    o.x = a.x * scale; o.y = a.y * scale; o.z = a.z * scale; o.w = a.w * scale;
    *(float4*)&out[(size_t)n * OUTD + o4] = o;
}

// ---------------------------------------------------------------------------
extern "C" void kernel_launch(void* const* d_in, const int* in_sizes, int n_in,
                              void* d_out, int out_size, void* d_ws, size_t ws_size,
                              hipStream_t stream)
{
    const float* x         = (const float*)d_in[0];
    const float* Wpool     = (const float*)d_in[1];
    const float* bpool     = (const float*)d_in[2];
    const float* Wconv     = (const float*)d_in[3];
    const float* bconv     = (const float*)d_in[4];
    const float* centroids = (const float*)d_in[5];
    const float* Wproj     = (const float*)d_in[6];
    const float* bproj     = (const float*)d_in[7];
    float* out = (float*)d_out;
    char*  wsb = (char*)d_ws;

    unsigned short* xn     = (unsigned short*)(wsb + OFF_XN);
    unsigned short* sa     = (unsigned short*)(wsb + OFF_SA);
    unsigned short* Wpk    = (unsigned short*)(wsb + OFF_WPK);
    unsigned short* Wck    = (unsigned short*)(wsb + OFF_WCK);
    float*          vladp  = (float*)(wsb + OFF_VLADP);
    float*          sasump = (float*)(wsb + OFF_SASUM);
    float*          vladn  = (float*)(wsb + OFF_VLADN);
    float*          outp   = (float*)(wsb + OFF_OUTP);

    pack_weights<<<dim3(9), 256, 0, stream>>>(Wpool, Wconv, Wpk, Wck);
    pool_norm_assign<<<dim3(SP / 16, NB), 256, 0, stream>>>(x, Wpk, bpool, Wck, bconv, xn, sa);
    vlad_mfma<<<dim3(NSPLIT, NB), 256, 0, stream>>>(xn, sa, vladp, sasump);
    vlad_finish<<<dim3(DD / 16, NB), 256, 0, stream>>>(vladp, sasump, centroids, vladn);
    proj_mfma<<<dim3(OUTD / 64, PSPLIT), 256, 0, stream>>>(vladn, Wproj, outp);
    final_norm_kernel<<<dim3(NB), 256, 0, stream>>>(outp, bproj, out);
}